// Round 1
// baseline (885.457 us; speedup 1.0000x reference)
//
#include <hip/hip_runtime.h>
#include <cstdint>
#include <cstddef>

#define D 128

// ---------------- CSR build ----------------

__global__ void k_count(const int* __restrict__ src, int* __restrict__ cnt, int ne2) {
    int e = blockIdx.x * blockDim.x + threadIdx.x;
    if (e < ne2) atomicAdd(&cnt[src[e]], 1);
}

__global__ void k_dinv(const int* __restrict__ cnt, float* __restrict__ dinv, int nn) {
    int i = blockIdx.x * blockDim.x + threadIdx.x;
    if (i < nn) {
        int c = cnt[i];
        dinv[i] = (c > 0) ? 1.0f / sqrtf((float)c) : 0.0f;
    }
}

// block-local exclusive scan of cnt -> rp, per-block totals -> bsum
__global__ void k_scan1(const int* __restrict__ cnt, int* __restrict__ rp,
                        int* __restrict__ bsum, int nn) {
    int i = blockIdx.x * 256 + threadIdx.x;
    int v = (i < nn) ? cnt[i] : 0;
    int lane = threadIdx.x & 63, wid = threadIdx.x >> 6;
    int x = v;
#pragma unroll
    for (int o = 1; o < 64; o <<= 1) {
        int y = __shfl_up(x, o);
        if (lane >= o) x += y;
    }
    __shared__ int wsum[4];
    __shared__ int woff[4];
    if (lane == 63) wsum[wid] = x;
    __syncthreads();
    if (threadIdx.x == 0) {
        int s = 0;
        for (int k = 0; k < 4; ++k) { woff[k] = s; s += wsum[k]; }
    }
    __syncthreads();
    int incl = x + woff[wid];
    if (i < nn) rp[i] = incl - v;            // exclusive within block
    if (threadIdx.x == 255) bsum[blockIdx.x] = incl;  // block total
}

// single-wave scan of block sums (nb <= ~600), writes rp[nn] = grand total
__global__ void k_scan2(int* __restrict__ bsum, int* __restrict__ rp, int nb, int nn) {
    int lane = threadIdx.x;  // 64 threads
    int carry = 0;
    for (int t = 0; t < nb; t += 64) {
        int v = (t + lane < nb) ? bsum[t + lane] : 0;
        int x = v;
#pragma unroll
        for (int o = 1; o < 64; o <<= 1) {
            int y = __shfl_up(x, o);
            if (lane >= o) x += y;
        }
        if (t + lane < nb) bsum[t + lane] = carry + x - v;  // exclusive
        carry += __shfl(x, 63);
    }
    if (lane == 0) rp[nn] = carry;
}

__global__ void k_scan3(int* __restrict__ rp, const int* __restrict__ bsum, int nn) {
    int i = blockIdx.x * 256 + threadIdx.x;
    if (i < nn) rp[i] += bsum[blockIdx.x];
}

__global__ void k_fill(const int* __restrict__ src, const int* __restrict__ dst,
                       const int* __restrict__ rp, int* __restrict__ fill,
                       int* __restrict__ col, int ne2) {
    int e = blockIdx.x * blockDim.x + threadIdx.x;
    if (e < ne2) {
        int s = src[e];
        int p = atomicAdd(&fill[s], 1);
        col[rp[s] + p] = dst[e];
    }
}

// ---------------- propagation ----------------

// acc = emb, x = emb  (emb is the concat of the two input tables)
__global__ void k_init(const float4* __restrict__ uw, const float4* __restrict__ iw,
                       float4* __restrict__ acc, float4* __restrict__ x,
                       int nu4, int ntot4) {
    int i = blockIdx.x * blockDim.x + threadIdx.x;
    if (i < ntot4) {
        float4 v = (i < nu4) ? uw[i] : iw[i - nu4];
        acc[i] = v;
        x[i] = v;
    }
}

// one wave per node: out[s] = dinv[s] * sum_{d in adj(s)} dinv[d] * x[d]
// lane owns float2 (2 of the 128 dims). acc[s] += out[s]; optionally write xout.
template <bool WRITE_X>
__global__ void k_spmm(const float2* __restrict__ xin, float2* __restrict__ xout,
                       float2* __restrict__ acc, const int* __restrict__ rp,
                       const int* __restrict__ col, const float* __restrict__ dinv,
                       int nn) {
    int w = (blockIdx.x * blockDim.x + threadIdx.x) >> 6;
    int lane = threadIdx.x & 63;
    if (w >= nn) return;
    int beg = rp[w], end = rp[w + 1];
    float ax = 0.f, ay = 0.f;
    for (int j = beg; j < end; j += 64) {
        int idx = 0;
        float wt = 0.f;
        if (j + lane < end) {
            idx = col[j + lane];
            wt = dinv[idx];
        }
        int cnt = min(64, end - j);
#pragma unroll 4
        for (int t = 0; t < cnt; ++t) {
            int d = __shfl(idx, t);
            float v = __shfl(wt, t);
            float2 xv = xin[(size_t)d * 64 + lane];
            ax = fmaf(v, xv.x, ax);
            ay = fmaf(v, xv.y, ay);
        }
    }
    float ds = dinv[w];
    ax *= ds;
    ay *= ds;
    size_t off = (size_t)w * 64 + lane;
    if (WRITE_X) xout[off] = make_float2(ax, ay);
    float2 c = acc[off];
    c.x += ax;
    c.y += ay;
    acc[off] = c;
}

__global__ void k_scale(float4* __restrict__ acc, int n4) {
    int i = blockIdx.x * blockDim.x + threadIdx.x;
    if (i < n4) {
        float4 v = acc[i];
        v.x *= 0.25f; v.y *= 0.25f; v.z *= 0.25f; v.w *= 0.25f;
        acc[i] = v;
    }
}

// ---------------- launch ----------------

extern "C" void kernel_launch(void* const* d_in, const int* in_sizes, int n_in,
                              void* d_out, int out_size, void* d_ws, size_t ws_size,
                              hipStream_t stream) {
    const float* uw = (const float*)d_in[0];
    const float* iw = (const float*)d_in[1];
    const int* ei = (const int*)d_in[2];

    const int NU = in_sizes[0] / D;       // 100000
    const int NI = in_sizes[1] / D;       // 50000
    const int NN = NU + NI;               // 150000
    const int NE2 = in_sizes[2] / 2;      // 2,000,000 directed edges
    const int* src = ei;
    const int* dst = ei + NE2;

    // workspace carve-up (256B aligned). Total ~156 MiB.
    char* p = (char*)d_ws;
    auto alloc = [&](size_t bytes) -> void* {
        void* r = (void*)p;
        p += (bytes + 255) & ~(size_t)255;
        return r;
    };
    int* cnt   = (int*)alloc((size_t)NN * 4);
    int* fillc = (int*)alloc((size_t)NN * 4);
    int* rp    = (int*)alloc((size_t)(NN + 1) * 4);
    int* bsum  = (int*)alloc(4096);
    float* dinv = (float*)alloc((size_t)NN * 4);
    int* col   = (int*)alloc((size_t)NE2 * 4);
    float* x1  = (float*)alloc((size_t)NN * D * 4);
    float* x2  = (float*)alloc((size_t)NN * D * 4);
    float* acc = (float*)d_out;

    // zero cnt + fillc in one shot (they are adjacent)
    size_t zspan = (char*)rp - (char*)cnt;
    hipMemsetAsync(cnt, 0, zspan, stream);

    int be = (NE2 + 255) / 256;
    int bn = (NN + 255) / 256;

    k_count<<<be, 256, 0, stream>>>(src, cnt, NE2);
    k_dinv<<<bn, 256, 0, stream>>>(cnt, dinv, NN);
    k_scan1<<<bn, 256, 0, stream>>>(cnt, rp, bsum, NN);
    k_scan2<<<1, 64, 0, stream>>>(bsum, rp, bn, NN);
    k_scan3<<<bn, 256, 0, stream>>>(rp, bsum, NN);
    k_fill<<<be, 256, 0, stream>>>(src, dst, rp, fillc, col, NE2);

    int ntot4 = NN * (D / 4);
    int nu4 = NU * (D / 4);
    int bi = (ntot4 + 255) / 256;
    k_init<<<bi, 256, 0, stream>>>((const float4*)uw, (const float4*)iw,
                                   (float4*)acc, (float4*)x1, nu4, ntot4);

    int bs = (NN + 3) / 4;  // 4 waves (nodes) per 256-thread block
    k_spmm<true><<<bs, 256, 0, stream>>>((const float2*)x1, (float2*)x2, (float2*)acc,
                                         rp, col, dinv, NN);
    k_spmm<true><<<bs, 256, 0, stream>>>((const float2*)x2, (float2*)x1, (float2*)acc,
                                         rp, col, dinv, NN);
    k_spmm<false><<<bs, 256, 0, stream>>>((const float2*)x1, (float2*)x2, (float2*)acc,
                                          rp, col, dinv, NN);

    k_scale<<<bi, 256, 0, stream>>>((float4*)acc, ntot4);
}

// Round 2
// 768.361 us; speedup vs baseline: 1.1524x; 1.1524x over previous
//
#include <hip/hip_runtime.h>
#include <hip/hip_fp16.h>
#include <cstdint>
#include <cstddef>

#define D 128

// ---------------- CSR build ----------------

__global__ void k_count(const int* __restrict__ src, int* __restrict__ cnt, int ne2) {
    int e = blockIdx.x * blockDim.x + threadIdx.x;
    if (e < ne2) atomicAdd(&cnt[src[e]], 1);
}

// block-local exclusive scan of cnt -> rp, per-block totals -> bsum, plus dinv
__global__ void k_scan1(const int* __restrict__ cnt, int* __restrict__ rp,
                        int* __restrict__ bsum, float* __restrict__ dinv, int nn) {
    int i = blockIdx.x * 256 + threadIdx.x;
    int v = (i < nn) ? cnt[i] : 0;
    if (i < nn) dinv[i] = (v > 0) ? 1.0f / sqrtf((float)v) : 0.0f;
    int lane = threadIdx.x & 63, wid = threadIdx.x >> 6;
    int x = v;
#pragma unroll
    for (int o = 1; o < 64; o <<= 1) {
        int y = __shfl_up(x, o);
        if (lane >= o) x += y;
    }
    __shared__ int wsum[4];
    __shared__ int woff[4];
    if (lane == 63) wsum[wid] = x;
    __syncthreads();
    if (threadIdx.x == 0) {
        int s = 0;
        for (int k = 0; k < 4; ++k) { woff[k] = s; s += wsum[k]; }
    }
    __syncthreads();
    int incl = x + woff[wid];
    if (i < nn) rp[i] = incl - v;            // exclusive within block
    if (threadIdx.x == 255) bsum[blockIdx.x] = incl;  // block total
}

// single-wave scan of block sums, writes rp[nn] = grand total
__global__ void k_scan2(int* __restrict__ bsum, int* __restrict__ rp, int nb, int nn) {
    int lane = threadIdx.x;  // 64 threads
    int carry = 0;
    for (int t = 0; t < nb; t += 64) {
        int v = (t + lane < nb) ? bsum[t + lane] : 0;
        int x = v;
#pragma unroll
        for (int o = 1; o < 64; o <<= 1) {
            int y = __shfl_up(x, o);
            if (lane >= o) x += y;
        }
        if (t + lane < nb) bsum[t + lane] = carry + x - v;  // exclusive
        carry += __shfl(x, 63);
    }
    if (lane == 0) rp[nn] = carry;
}

__global__ void k_scan3(int* __restrict__ rp, const int* __restrict__ bsum, int nn) {
    int i = blockIdx.x * 256 + threadIdx.x;
    if (i < nn) rp[i] += bsum[blockIdx.x];
}

__global__ void k_fill(const int* __restrict__ src, const int* __restrict__ dst,
                       const int* __restrict__ rp, int* __restrict__ fill,
                       int* __restrict__ col, int ne2) {
    int e = blockIdx.x * blockDim.x + threadIdx.x;
    if (e < ne2) {
        int s = src[e];
        int p = atomicAdd(&fill[s], 1);
        col[rp[s] + p] = dst[e];
    }
}

// ---------------- propagation ----------------

// x0h = fp16(concat(uw, iw))
__global__ void k_tohalf(const float2* __restrict__ uw, const float2* __restrict__ iw,
                         __half2* __restrict__ x0, int nu2, int ntot2) {
    int g = blockIdx.x * blockDim.x + threadIdx.x;
    if (g < ntot2) {
        float2 v = (g < nu2) ? uw[g] : iw[g - nu2];
        x0[g] = __floats2half2_rn(v.x, v.y);
    }
}

// one wave per node: xout[s] = fp16( dinv[s] * sum_{d in adj(s)} dinv[d] * xin[d] )
// lane owns 2 of the 128 dims (one half2 = 4B load per neighbor).
__global__ void k_spmm(const __half2* __restrict__ xin, __half2* __restrict__ xout,
                       const int* __restrict__ rp, const int* __restrict__ col,
                       const float* __restrict__ dinv, int nn) {
    int w = (blockIdx.x * blockDim.x + threadIdx.x) >> 6;
    int lane = threadIdx.x & 63;
    if (w >= nn) return;
    int beg = rp[w], end = rp[w + 1];
    float ax = 0.f, ay = 0.f;
    for (int j = beg; j < end; j += 64) {
        int idx = 0;
        float wt = 0.f;
        if (j + lane < end) {
            idx = col[j + lane];
            wt = dinv[idx];
        }
        int cnt = min(64, end - j);
#pragma unroll 4
        for (int t = 0; t < cnt; ++t) {
            int d = __shfl(idx, t);
            float v = __shfl(wt, t);
            float2 xv = __half22float2(xin[(size_t)d * 64 + lane]);
            ax = fmaf(v, xv.x, ax);
            ay = fmaf(v, xv.y, ay);
        }
    }
    float ds = dinv[w];
    xout[(size_t)w * 64 + lane] = __floats2half2_rn(ax * ds, ay * ds);
}

// out = (emb + x1 + x2 + x3) / 4, emb read in fp32 (no extra rounding on layer 0)
__global__ void k_combine(const float2* __restrict__ uw, const float2* __restrict__ iw,
                          const __half2* __restrict__ x1, const __half2* __restrict__ x2,
                          const __half2* __restrict__ x3, float2* __restrict__ out,
                          int nu2, int ntot2) {
    int g = blockIdx.x * blockDim.x + threadIdx.x;
    if (g >= ntot2) return;
    float2 e = (g < nu2) ? uw[g] : iw[g - nu2];
    float2 a = __half22float2(x1[g]);
    float2 b = __half22float2(x2[g]);
    float2 c = __half22float2(x3[g]);
    float2 r;
    r.x = 0.25f * (e.x + a.x + b.x + c.x);
    r.y = 0.25f * (e.y + a.y + b.y + c.y);
    out[g] = r;
}

// ---------------- launch ----------------

extern "C" void kernel_launch(void* const* d_in, const int* in_sizes, int n_in,
                              void* d_out, int out_size, void* d_ws, size_t ws_size,
                              hipStream_t stream) {
    const float* uw = (const float*)d_in[0];
    const float* iw = (const float*)d_in[1];
    const int* ei = (const int*)d_in[2];

    const int NU = in_sizes[0] / D;       // 100000
    const int NI = in_sizes[1] / D;       // 50000
    const int NN = NU + NI;               // 150000
    const int NE2 = in_sizes[2] / 2;      // 2,000,000 directed edges
    const int* src = ei;
    const int* dst = ei + NE2;

    // workspace carve-up (256B aligned). Total ~126 MiB.
    char* p = (char*)d_ws;
    auto alloc = [&](size_t bytes) -> void* {
        void* r = (void*)p;
        p += (bytes + 255) & ~(size_t)255;
        return r;
    };
    int* cnt    = (int*)alloc((size_t)NN * 4);
    int* fillc  = (int*)alloc((size_t)NN * 4);
    int* rp     = (int*)alloc((size_t)(NN + 1) * 4);
    int* bsum   = (int*)alloc(4096);
    float* dinv = (float*)alloc((size_t)NN * 4);
    int* col    = (int*)alloc((size_t)NE2 * 4);
    __half2* xa = (__half2*)alloc((size_t)NN * D * 2);  // x0, then reused as x3
    __half2* xb = (__half2*)alloc((size_t)NN * D * 2);  // x1
    __half2* xc = (__half2*)alloc((size_t)NN * D * 2);  // x2
    float* outp = (float*)d_out;

    // zero cnt + fillc in one shot (adjacent)
    size_t zspan = (char*)rp - (char*)cnt;
    hipMemsetAsync(cnt, 0, zspan, stream);

    int be = (NE2 + 255) / 256;
    int bn = (NN + 255) / 256;

    k_count<<<be, 256, 0, stream>>>(src, cnt, NE2);
    k_scan1<<<bn, 256, 0, stream>>>(cnt, rp, bsum, dinv, NN);
    k_scan2<<<1, 64, 0, stream>>>(bsum, rp, bn, NN);
    k_scan3<<<bn, 256, 0, stream>>>(rp, bsum, NN);
    k_fill<<<be, 256, 0, stream>>>(src, dst, rp, fillc, col, NE2);

    int ntot2 = NN * (D / 2);
    int nu2 = NU * (D / 2);
    int bi = (ntot2 + 255) / 256;
    k_tohalf<<<bi, 256, 0, stream>>>((const float2*)uw, (const float2*)iw, xa, nu2, ntot2);

    int bs = (NN + 3) / 4;  // 4 waves (nodes) per 256-thread block
    k_spmm<<<bs, 256, 0, stream>>>(xa, xb, rp, col, dinv, NN);  // x1 = A x0
    k_spmm<<<bs, 256, 0, stream>>>(xb, xc, rp, col, dinv, NN);  // x2 = A x1
    k_spmm<<<bs, 256, 0, stream>>>(xc, xa, rp, col, dinv, NN);  // x3 = A x2 (reuse x0 buf)

    k_combine<<<bi, 256, 0, stream>>>((const float2*)uw, (const float2*)iw,
                                      xb, xc, xa, (float2*)outp, nu2, ntot2);
}

// Round 3
// 573.817 us; speedup vs baseline: 1.5431x; 1.3390x over previous
//
#include <hip/hip_runtime.h>
#include <hip/hip_fp16.h>
#include <cstdint>
#include <cstddef>

#define D 128

// ---------------- CSR build ----------------

__global__ void k_count(const int* __restrict__ src, int* __restrict__ cnt, int ne2) {
    int e = blockIdx.x * blockDim.x + threadIdx.x;
    if (e < ne2) atomicAdd(&cnt[src[e]], 1);
}

// block-local exclusive scan of cnt -> rp, per-block totals -> bsum, plus dinv
__global__ void k_scan1(const int* __restrict__ cnt, int* __restrict__ rp,
                        int* __restrict__ bsum, float* __restrict__ dinv, int nn) {
    int i = blockIdx.x * 256 + threadIdx.x;
    int v = (i < nn) ? cnt[i] : 0;
    if (i < nn) dinv[i] = (v > 0) ? 1.0f / sqrtf((float)v) : 0.0f;
    int lane = threadIdx.x & 63, wid = threadIdx.x >> 6;
    int x = v;
#pragma unroll
    for (int o = 1; o < 64; o <<= 1) {
        int y = __shfl_up(x, o);
        if (lane >= o) x += y;
    }
    __shared__ int wsum[4];
    __shared__ int woff[4];
    if (lane == 63) wsum[wid] = x;
    __syncthreads();
    if (threadIdx.x == 0) {
        int s = 0;
        for (int k = 0; k < 4; ++k) { woff[k] = s; s += wsum[k]; }
    }
    __syncthreads();
    int incl = x + woff[wid];
    if (i < nn) rp[i] = incl - v;            // exclusive within block
    if (threadIdx.x == 255) bsum[blockIdx.x] = incl;  // block total
}

__global__ void k_scan2(int* __restrict__ bsum, int* __restrict__ rp, int nb, int nn) {
    int lane = threadIdx.x;  // 64 threads
    int carry = 0;
    for (int t = 0; t < nb; t += 64) {
        int v = (t + lane < nb) ? bsum[t + lane] : 0;
        int x = v;
#pragma unroll
        for (int o = 1; o < 64; o <<= 1) {
            int y = __shfl_up(x, o);
            if (lane >= o) x += y;
        }
        if (t + lane < nb) bsum[t + lane] = carry + x - v;  // exclusive
        carry += __shfl(x, 63);
    }
    if (lane == 0) rp[nn] = carry;
}

__global__ void k_scan3(int* __restrict__ rp, const int* __restrict__ bsum, int nn) {
    int i = blockIdx.x * 256 + threadIdx.x;
    if (i < nn) rp[i] += bsum[blockIdx.x];
}

// fill CSR: edges[o] = {dst, bits(dinv[dst])} -- per-edge weight precomputed
__global__ void k_fill(const int* __restrict__ src, const int* __restrict__ dst,
                       const int* __restrict__ rp, int* __restrict__ fill,
                       int2* __restrict__ edges, const float* __restrict__ dinv, int ne2) {
    int e = blockIdx.x * blockDim.x + threadIdx.x;
    if (e < ne2) {
        int s = src[e], d = dst[e];
        int p = atomicAdd(&fill[s], 1);
        edges[rp[s] + p] = make_int2(d, __float_as_int(dinv[d]));
    }
}

// ---------------- propagation ----------------

__global__ void k_tohalf(const float2* __restrict__ uw, const float2* __restrict__ iw,
                         __half2* __restrict__ x0, int nu2, int ntot2) {
    int g = blockIdx.x * blockDim.x + threadIdx.x;
    if (g < ntot2) {
        float2 v = (g < nu2) ? uw[g] : iw[g - nu2];
        x0[g] = __floats2half2_rn(v.x, v.y);
    }
}

// One wave = 4 nodes (16 lanes each). Each lane loads float4 (8 fp16 dims) of a
// neighbor row -> full 256B row per wave-instruction, 4 independent gather
// streams per wave. Neighbor idx+weight batch-loaded (int2) per 16 neighbors,
// broadcast in-register via __shfl. Group's 16 lanes hold the whole output row.
// FUSE: layer-3 epilogue reads emb(fp32)+x1+x2 rows and writes d_out directly.
template <bool FUSE>
__global__ __launch_bounds__(256)
void k_spmm(const float4* __restrict__ xin, float4* __restrict__ xout,
            const int* __restrict__ rp, const int2* __restrict__ edges,
            const float* __restrict__ dinv,
            const float4* __restrict__ uw, const float4* __restrict__ iw,
            const float4* __restrict__ x1h, float4* __restrict__ outp,
            int nu, int nn) {
    int wave = (blockIdx.x * blockDim.x + threadIdx.x) >> 6;
    int lane = threadIdx.x & 63;
    int g = lane >> 4, l16 = lane & 15;
    int node = wave * 4 + g;
    int beg = 0, end = 0;
    if (node < nn) { beg = rp[node]; end = rp[node + 1]; }
    float acc[8];
#pragma unroll
    for (int k = 0; k < 8; ++k) acc[k] = 0.f;

    int srcl = g << 4;
    for (int base = beg; base < end; base += 16) {
        int p = base + l16;
        int2 ev = make_int2(0, 0);
        if (p < end) ev = edges[p];
        int m = min(16, end - base);
#pragma unroll 4
        for (int t = 0; t < m; ++t) {
            int d = __shfl(ev.x, srcl + t);
            float wv = __uint_as_float((unsigned)__shfl(ev.y, srcl + t));
            float4 rv = xin[(size_t)d * 16 + l16];
            const __half2* hp = reinterpret_cast<const __half2*>(&rv);
#pragma unroll
            for (int k = 0; k < 4; ++k) {
                float2 f = __half22float2(hp[k]);
                acc[2 * k]     = fmaf(wv, f.x, acc[2 * k]);
                acc[2 * k + 1] = fmaf(wv, f.y, acc[2 * k + 1]);
            }
        }
    }
    if (node >= nn) return;
    float s = dinv[node];
    if (!FUSE) {
        __half2 h[4];
#pragma unroll
        for (int k = 0; k < 4; ++k)
            h[k] = __floats2half2_rn(s * acc[2 * k], s * acc[2 * k + 1]);
        xout[(size_t)node * 16 + l16] = *reinterpret_cast<const float4*>(h);
    } else {
        size_t r16 = (size_t)node * 16 + l16;
        float4 av = x1h[r16];   // x1 row chunk (fp16)
        float4 bv = xin[r16];   // x2 row chunk (fp16) -- same buffer we gathered
        const __half2* ap = reinterpret_cast<const __half2*>(&av);
        const __half2* bp = reinterpret_cast<const __half2*>(&bv);
        float4 e0, e1;
        if (node < nu) {
            size_t rr = (size_t)node * 32 + 2 * l16;
            e0 = uw[rr]; e1 = uw[rr + 1];
        } else {
            size_t rr = (size_t)(node - nu) * 32 + 2 * l16;
            e0 = iw[rr]; e1 = iw[rr + 1];
        }
        float o[8];
#pragma unroll
        for (int k = 0; k < 4; ++k) {
            float2 fa = __half22float2(ap[k]);
            float2 fb = __half22float2(bp[k]);
            o[2 * k]     = fa.x + fb.x + s * acc[2 * k];
            o[2 * k + 1] = fa.y + fb.y + s * acc[2 * k + 1];
        }
        float4 w0 = make_float4(0.25f * (e0.x + o[0]), 0.25f * (e0.y + o[1]),
                                0.25f * (e0.z + o[2]), 0.25f * (e0.w + o[3]));
        float4 w1 = make_float4(0.25f * (e1.x + o[4]), 0.25f * (e1.y + o[5]),
                                0.25f * (e1.z + o[6]), 0.25f * (e1.w + o[7]));
        size_t r32 = (size_t)node * 32 + 2 * l16;
        outp[r32] = w0;
        outp[r32 + 1] = w1;
    }
}

// ---------------- launch ----------------

extern "C" void kernel_launch(void* const* d_in, const int* in_sizes, int n_in,
                              void* d_out, int out_size, void* d_ws, size_t ws_size,
                              hipStream_t stream) {
    const float* uw = (const float*)d_in[0];
    const float* iw = (const float*)d_in[1];
    const int* ei = (const int*)d_in[2];

    const int NU = in_sizes[0] / D;       // 100000
    const int NI = in_sizes[1] / D;       // 50000
    const int NN = NU + NI;               // 150000
    const int NE2 = in_sizes[2] / 2;      // 2,000,000 directed edges
    const int* src = ei;
    const int* dst = ei + NE2;

    char* p = (char*)d_ws;
    auto alloc = [&](size_t bytes) -> void* {
        void* r = (void*)p;
        p += (bytes + 255) & ~(size_t)255;
        return r;
    };
    int* cnt    = (int*)alloc((size_t)NN * 4);
    int* fillc  = (int*)alloc((size_t)NN * 4);
    int* rp     = (int*)alloc((size_t)(NN + 1) * 4);
    int* bsum   = (int*)alloc(4096);
    float* dinv = (float*)alloc((size_t)NN * 4);
    int2* edges = (int2*)alloc((size_t)NE2 * 8);
    __half2* xa = (__half2*)alloc((size_t)NN * D * 2);  // x0
    __half2* xb = (__half2*)alloc((size_t)NN * D * 2);  // x1
    __half2* xc = (__half2*)alloc((size_t)NN * D * 2);  // x2
    float* outp = (float*)d_out;

    size_t zspan = (char*)rp - (char*)cnt;
    hipMemsetAsync(cnt, 0, zspan, stream);

    int be = (NE2 + 255) / 256;
    int bn = (NN + 255) / 256;

    k_count<<<be, 256, 0, stream>>>(src, cnt, NE2);
    k_scan1<<<bn, 256, 0, stream>>>(cnt, rp, bsum, dinv, NN);
    k_scan2<<<1, 64, 0, stream>>>(bsum, rp, bn, NN);
    k_scan3<<<bn, 256, 0, stream>>>(rp, bsum, NN);
    k_fill<<<be, 256, 0, stream>>>(src, dst, rp, fillc, edges, dinv, NE2);

    int ntot2 = NN * (D / 2);
    int nu2 = NU * (D / 2);
    int bi = (ntot2 + 255) / 256;
    k_tohalf<<<bi, 256, 0, stream>>>((const float2*)uw, (const float2*)iw, xa, nu2, ntot2);

    int bs = (NN + 15) / 16;  // 4 waves/block, 4 nodes per wave
    k_spmm<false><<<bs, 256, 0, stream>>>((const float4*)xa, (float4*)xb, rp, edges, dinv,
                                          nullptr, nullptr, nullptr, nullptr, NU, NN);
    k_spmm<false><<<bs, 256, 0, stream>>>((const float4*)xb, (float4*)xc, rp, edges, dinv,
                                          nullptr, nullptr, nullptr, nullptr, NU, NN);
    k_spmm<true><<<bs, 256, 0, stream>>>((const float4*)xc, nullptr, rp, edges, dinv,
                                         (const float4*)uw, (const float4*)iw,
                                         (const float4*)xb, (float4*)outp, NU, NN);
}

// Round 5
// 462.206 us; speedup vs baseline: 1.9157x; 1.2415x over previous
//
#include <hip/hip_runtime.h>
#include <hip/hip_fp16.h>
#include <cstdint>
#include <cstddef>

#define D 128
#define BSH 9              // 512 nodes per bucket
#define BNODES 512
#define NBMAX 512          // max buckets (supports NN up to 262144)
#define CCHUNK 8192        // edges per block in hist/scatter

// ---------------- bucketed CSR build ----------------

// A: per-bucket histogram (LDS-aggregated)
__global__ __launch_bounds__(256)
void k_hist(const int* __restrict__ src, int* __restrict__ bhist, int ne2, int nb) {
    __shared__ int lc[NBMAX];
    for (int i = threadIdx.x; i < nb; i += 256) lc[i] = 0;
    __syncthreads();
    int base = blockIdx.x * CCHUNK;
    int lim = min(base + CCHUNK, ne2);
    for (int e = base + threadIdx.x; e < lim; e += 256)
        atomicAdd(&lc[src[e] >> BSH], 1);
    __syncthreads();
    for (int i = threadIdx.x; i < nb; i += 256)
        if (lc[i]) atomicAdd(&bhist[i], lc[i]);
}

// B: scan bucket counts -> bbase (exclusive), init bfill, write totals
__global__ void k_bscan(const int* __restrict__ bhist, int* __restrict__ bbase,
                        int* __restrict__ bfill, int* __restrict__ rp,
                        int nb, int nn, int ne2) {
    __shared__ int a[NBMAX], b2[NBMAX];
    int t = threadIdx.x;  // NBMAX threads
    int v = (t < nb) ? bhist[t] : 0;
    a[t] = v;
    __syncthreads();
    int* cur = a; int* nxt = b2;
    for (int o = 1; o < NBMAX; o <<= 1) {
        int x = cur[t];
        if (t >= o) x += cur[t - o];
        nxt[t] = x;
        __syncthreads();
        int* tm = cur; cur = nxt; nxt = tm;
    }
    int excl = cur[t] - v;
    if (t < nb) { bbase[t] = excl; bfill[t] = excl; }
    if (t == 0) { bbase[nb] = ne2; rp[nn] = ne2; }
}

// C: scatter edges into bucket regions; LDS counting-sort per block so each
// block writes one contiguous run per bucket (writeback ~= payload).
__global__ __launch_bounds__(256)
void k_scatter(const int* __restrict__ src, const int* __restrict__ dst,
               int* __restrict__ bfill, int2* __restrict__ tmp, int ne2, int nb) {
    __shared__ int lc[NBMAX], lb[NBMAX];
    for (int i = threadIdx.x; i < nb; i += 256) lc[i] = 0;
    __syncthreads();
    int base = blockIdx.x * CCHUNK;
    int rec[CCHUNK / 256];
#pragma unroll
    for (int i = 0; i < CCHUNK / 256; ++i) {
        int e = base + i * 256 + threadIdx.x;
        rec[i] = -1;
        if (e < ne2) {
            int b = src[e] >> BSH;
            int r = atomicAdd(&lc[b], 1);
            rec[i] = (r << BSH) | b;   // r < 8192 (13b) | b < 512 (9b)
        }
    }
    __syncthreads();
    for (int i = threadIdx.x; i < nb; i += 256)
        if (lc[i]) lb[i] = atomicAdd(&bfill[i], lc[i]);
    __syncthreads();
#pragma unroll
    for (int i = 0; i < CCHUNK / 256; ++i) {
        if (rec[i] >= 0) {
            int e = base + i * 256 + threadIdx.x;
            int b = rec[i] & (BNODES - 1);
            int r = rec[i] >> BSH;
            tmp[lb[b] + r] = make_int2(src[e], dst[e]);
        }
    }
}

// D: one block per bucket: LDS per-node count -> LDS scan -> rp/dinv,
// then place col (dst only) into the bucket's L2-resident window.
__global__ __launch_bounds__(256)
void k_build(const int2* __restrict__ tmp, const int* __restrict__ bbase,
             int* __restrict__ col, int* __restrict__ rp, float* __restrict__ dinv,
             int nn) {
    __shared__ int cnt[BNODES];
    __shared__ int off[BNODES];
    __shared__ int wtot[4], woff[4];
    int bkt = blockIdx.x;
    int n0 = bkt << BSH;
    int nloc = min(BNODES, nn - n0);
    int ebeg = bbase[bkt], eend = bbase[bkt + 1];
    for (int i = threadIdx.x; i < BNODES; i += 256) cnt[i] = 0;
    __syncthreads();
    for (int e = ebeg + threadIdx.x; e < eend; e += 256)
        atomicAdd(&cnt[tmp[e].x - n0], 1);
    __syncthreads();
    // block exclusive scan over cnt[0..512): thread owns 2 consecutive entries
    int t = threadIdx.x;
    int c0 = cnt[2 * t], c1 = cnt[2 * t + 1];
    int s = c0 + c1;
    int lane = t & 63, wid = t >> 6;
    int x = s;
#pragma unroll
    for (int o = 1; o < 64; o <<= 1) {
        int y = __shfl_up(x, o);
        if (lane >= o) x += y;
    }
    if (lane == 63) wtot[wid] = x;
    __syncthreads();
    if (t == 0) { int a = 0; for (int k = 0; k < 4; ++k) { woff[k] = a; a += wtot[k]; } }
    __syncthreads();
    int eb = woff[wid] + x - s;
    off[2 * t] = eb;
    off[2 * t + 1] = eb + c0;
    __syncthreads();
    for (int i = threadIdx.x; i < nloc; i += 256) {
        rp[n0 + i] = ebeg + off[i];
        int c = cnt[i];
        dinv[n0 + i] = (c > 0) ? rsqrtf((float)c) : 0.0f;
    }
    __syncthreads();
    for (int i = threadIdx.x; i < BNODES; i += 256) cnt[i] = 0;  // reuse as fill
    __syncthreads();
    for (int e = ebeg + threadIdx.x; e < eend; e += 256) {
        int2 ed = tmp[e];
        int sl = ed.x - n0;
        int r = atomicAdd(&cnt[sl], 1);
        col[ebeg + off[sl] + r] = ed.y;
    }
}

// ---------------- propagation ----------------

__global__ void k_tohalf(const float2* __restrict__ uw, const float2* __restrict__ iw,
                         __half2* __restrict__ x0, int nu2, int ntot2) {
    int g = blockIdx.x * blockDim.x + threadIdx.x;
    if (g < ntot2) {
        float2 v = (g < nu2) ? uw[g] : iw[g - nu2];
        x0[g] = __floats2half2_rn(v.x, v.y);
    }
}

// One wave = 4 nodes (16 lanes each). Lane loads float4 (8 fp16 dims) of a
// neighbor row. Neighbor idx batch-loaded per 16; dinv gathered per-lane
// (independent chain, L2-hot 600KB), both broadcast via __shfl.
template <bool FUSE>
__global__ __launch_bounds__(256)
void k_spmm(const float4* __restrict__ xin, float4* __restrict__ xout,
            const int* __restrict__ rp, const int* __restrict__ col,
            const float* __restrict__ dinv,
            const float4* __restrict__ uw, const float4* __restrict__ iw,
            const float4* __restrict__ x1h, float4* __restrict__ outp,
            int nu, int nn) {
    int wave = (blockIdx.x * blockDim.x + threadIdx.x) >> 6;
    int lane = threadIdx.x & 63;
    int g = lane >> 4, l16 = lane & 15;
    int node = wave * 4 + g;
    int beg = 0, end = 0;
    if (node < nn) { beg = rp[node]; end = rp[node + 1]; }
    float acc[8];
#pragma unroll
    for (int k = 0; k < 8; ++k) acc[k] = 0.f;

    int srcl = g << 4;
    for (int base = beg; base < end; base += 16) {
        int p = base + l16;
        int d = 0;
        float wt = 0.f;
        if (p < end) {
            d = col[p];
            wt = dinv[d];
        }
        int m = min(16, end - base);
#pragma unroll 8
        for (int t = 0; t < m; ++t) {
            int dd = __shfl(d, srcl + t);
            float wv = __shfl(wt, srcl + t);
            float4 rv = xin[(size_t)dd * 16 + l16];
            const __half2* hp = reinterpret_cast<const __half2*>(&rv);
#pragma unroll
            for (int k = 0; k < 4; ++k) {
                float2 f = __half22float2(hp[k]);
                acc[2 * k]     = fmaf(wv, f.x, acc[2 * k]);
                acc[2 * k + 1] = fmaf(wv, f.y, acc[2 * k + 1]);
            }
        }
    }
    if (node >= nn) return;
    float s = dinv[node];
    if (!FUSE) {
        __half2 h[4];
#pragma unroll
        for (int k = 0; k < 4; ++k)
            h[k] = __floats2half2_rn(s * acc[2 * k], s * acc[2 * k + 1]);
        xout[(size_t)node * 16 + l16] = *reinterpret_cast<const float4*>(h);
    } else {
        size_t r16 = (size_t)node * 16 + l16;
        float4 av = x1h[r16];   // x1 row chunk (fp16)
        float4 bv = xin[r16];   // x2 row chunk (fp16)
        const __half2* ap = reinterpret_cast<const __half2*>(&av);
        const __half2* bp = reinterpret_cast<const __half2*>(&bv);
        float4 e0, e1;
        if (node < nu) {
            size_t rr = (size_t)node * 32 + 2 * l16;
            e0 = uw[rr]; e1 = uw[rr + 1];
        } else {
            size_t rr = (size_t)(node - nu) * 32 + 2 * l16;
            e0 = iw[rr]; e1 = iw[rr + 1];
        }
        float o[8];
#pragma unroll
        for (int k = 0; k < 4; ++k) {
            float2 fa = __half22float2(ap[k]);
            float2 fb = __half22float2(bp[k]);
            o[2 * k]     = fa.x + fb.x + s * acc[2 * k];
            o[2 * k + 1] = fa.y + fb.y + s * acc[2 * k + 1];
        }
        float4 w0 = make_float4(0.25f * (e0.x + o[0]), 0.25f * (e0.y + o[1]),
                                0.25f * (e0.z + o[2]), 0.25f * (e0.w + o[3]));
        float4 w1 = make_float4(0.25f * (e1.x + o[4]), 0.25f * (e1.y + o[5]),
                                0.25f * (e1.z + o[6]), 0.25f * (e1.w + o[7]));
        size_t r32 = (size_t)node * 32 + 2 * l16;
        outp[r32] = w0;
        outp[r32 + 1] = w1;
    }
}

// ---------------- launch ----------------

extern "C" void kernel_launch(void* const* d_in, const int* in_sizes, int n_in,
                              void* d_out, int out_size, void* d_ws, size_t ws_size,
                              hipStream_t stream) {
    const float* uw = (const float*)d_in[0];
    const float* iw = (const float*)d_in[1];
    const int* ei = (const int*)d_in[2];

    const int NU = in_sizes[0] / D;       // 100000
    const int NI = in_sizes[1] / D;       // 50000
    const int NN = NU + NI;               // 150000
    const int NE2 = in_sizes[2] / 2;      // 2,000,000 directed edges
    const int* src = ei;
    const int* dst = ei + NE2;
    const int NB = (NN + BNODES - 1) >> BSH;   // 293

    char* p = (char*)d_ws;
    auto alloc = [&](size_t bytes) -> void* {
        void* r = (void*)p;
        p += (bytes + 255) & ~(size_t)255;
        return r;
    };
    int* bhist  = (int*)alloc(NBMAX * 4);
    int* bbase  = (int*)alloc((NBMAX + 1) * 4);
    int* bfill  = (int*)alloc(NBMAX * 4);
    int* rp     = (int*)alloc((size_t)(NN + 1) * 4);
    float* dinv = (float*)alloc((size_t)NN * 4);
    int2* tmp   = (int2*)alloc((size_t)NE2 * 8);
    int* col    = (int*)alloc((size_t)NE2 * 4);
    __half2* xa = (__half2*)alloc((size_t)NN * D * 2);  // x0 / x3
    __half2* xb = (__half2*)alloc((size_t)NN * D * 2);  // x1
    __half2* xc = (__half2*)alloc((size_t)NN * D * 2);  // x2
    float* outp = (float*)d_out;

    hipMemsetAsync(bhist, 0, NBMAX * 4, stream);

    int bce = (NE2 + CCHUNK - 1) / CCHUNK;
    k_hist<<<bce, 256, 0, stream>>>(src, bhist, NE2, NB);
    k_bscan<<<1, NBMAX, 0, stream>>>(bhist, bbase, bfill, rp, NB, NN, NE2);
    k_scatter<<<bce, 256, 0, stream>>>(src, dst, bfill, tmp, NE2, NB);
    k_build<<<NB, 256, 0, stream>>>(tmp, bbase, col, rp, dinv, NN);

    int ntot2 = NN * (D / 2);
    int nu2 = NU * (D / 2);
    int bi = (ntot2 + 255) / 256;
    k_tohalf<<<bi, 256, 0, stream>>>((const float2*)uw, (const float2*)iw, xa, nu2, ntot2);

    int bs = (NN + 15) / 16;  // 4 waves/block, 4 nodes per wave
    k_spmm<false><<<bs, 256, 0, stream>>>((const float4*)xa, (float4*)xb, rp, col, dinv,
                                          nullptr, nullptr, nullptr, nullptr, NU, NN);
    k_spmm<false><<<bs, 256, 0, stream>>>((const float4*)xb, (float4*)xc, rp, col, dinv,
                                          nullptr, nullptr, nullptr, nullptr, NU, NN);
    k_spmm<true><<<bs, 256, 0, stream>>>((const float4*)xc, nullptr, rp, col, dinv,
                                         (const float4*)uw, (const float4*)iw,
                                         (const float4*)xb, (float4*)outp, NU, NN);
}

// Round 6
// 442.531 us; speedup vs baseline: 2.0009x; 1.0445x over previous
//
#include <hip/hip_runtime.h>
#include <hip/hip_fp16.h>
#include <cstdint>
#include <cstddef>

#define D 128
#define BSH 9              // 512 nodes per bucket
#define BNODES 512
#define NBMAX 512          // max buckets (supports NN up to 262144)
#define CCHUNK 8192        // edges per block in hist/scatter

// ---------------- bucketed CSR build ----------------

// A: per-bucket histogram (blocks [0, nbh)) + emb->fp16 (blocks [nbh, nbh+nbt))
__global__ __launch_bounds__(256)
void k_hist_tohalf(const int* __restrict__ src, int* __restrict__ bhist,
                   int ne2, int nb, int nbh,
                   const float2* __restrict__ uw, const float2* __restrict__ iw,
                   __half2* __restrict__ x0, int nu2, int ntot2) {
    if ((int)blockIdx.x < nbh) {
        __shared__ int lc[NBMAX];
        for (int i = threadIdx.x; i < nb; i += 256) lc[i] = 0;
        __syncthreads();
        int base = blockIdx.x * CCHUNK;
        int lim = min(base + CCHUNK, ne2);
        for (int e = base + threadIdx.x; e < lim; e += 256)
            atomicAdd(&lc[src[e] >> BSH], 1);
        __syncthreads();
        for (int i = threadIdx.x; i < nb; i += 256)
            if (lc[i]) atomicAdd(&bhist[i], lc[i]);
    } else {
        int g = (blockIdx.x - nbh) * 256 + threadIdx.x;
        if (g < ntot2) {
            float2 v = (g < nu2) ? uw[g] : iw[g - nu2];
            x0[g] = __floats2half2_rn(v.x, v.y);
        }
    }
}

// B: scan bucket counts -> bbase (exclusive), init bfill, write totals
__global__ void k_bscan(const int* __restrict__ bhist, int* __restrict__ bbase,
                        int* __restrict__ bfill, int* __restrict__ rp,
                        int nb, int nn, int ne2) {
    __shared__ int a[NBMAX], b2[NBMAX];
    int t = threadIdx.x;  // NBMAX threads
    int v = (t < nb) ? bhist[t] : 0;
    a[t] = v;
    __syncthreads();
    int* cur = a; int* nxt = b2;
    for (int o = 1; o < NBMAX; o <<= 1) {
        int x = cur[t];
        if (t >= o) x += cur[t - o];
        nxt[t] = x;
        __syncthreads();
        int* tm = cur; cur = nxt; nxt = tm;
    }
    int excl = cur[t] - v;
    if (t < nb) { bbase[t] = excl; bfill[t] = excl; }
    if (t == 0) { bbase[nb] = ne2; rp[nn] = ne2; }
}

// C: scatter edges into bucket regions; LDS counting-sort per block so each
// block writes one contiguous run per bucket (writeback ~= payload).
__global__ __launch_bounds__(256)
void k_scatter(const int* __restrict__ src, const int* __restrict__ dst,
               int* __restrict__ bfill, int2* __restrict__ tmp, int ne2, int nb) {
    __shared__ int lc[NBMAX], lb[NBMAX];
    for (int i = threadIdx.x; i < nb; i += 256) lc[i] = 0;
    __syncthreads();
    int base = blockIdx.x * CCHUNK;
    int rec[CCHUNK / 256];
#pragma unroll
    for (int i = 0; i < CCHUNK / 256; ++i) {
        int e = base + i * 256 + threadIdx.x;
        rec[i] = -1;
        if (e < ne2) {
            int b = src[e] >> BSH;
            int r = atomicAdd(&lc[b], 1);
            rec[i] = (r << BSH) | b;   // r < 8192 (13b) | b < 512 (9b)
        }
    }
    __syncthreads();
    for (int i = threadIdx.x; i < nb; i += 256)
        if (lc[i]) lb[i] = atomicAdd(&bfill[i], lc[i]);
    __syncthreads();
#pragma unroll
    for (int i = 0; i < CCHUNK / 256; ++i) {
        if (rec[i] >= 0) {
            int e = base + i * 256 + threadIdx.x;
            int b = rec[i] & (BNODES - 1);
            int r = rec[i] >> BSH;
            tmp[lb[b] + r] = make_int2(src[e], dst[e]);
        }
    }
}

// D: one block per bucket: LDS per-node count -> LDS scan -> rp/dinv/dinv2/rinv,
// then place col (dst only) into the bucket's L2-resident window.
__global__ __launch_bounds__(256)
void k_build(const int2* __restrict__ tmp, const int* __restrict__ bbase,
             int* __restrict__ col, int* __restrict__ rp, float* __restrict__ dinv,
             float* __restrict__ dinv2, float* __restrict__ rinv, int nn) {
    __shared__ int cnt[BNODES];
    __shared__ int off[BNODES];
    __shared__ int wtot[4], woff[4];
    int bkt = blockIdx.x;
    int n0 = bkt << BSH;
    int nloc = min(BNODES, nn - n0);
    int ebeg = bbase[bkt], eend = bbase[bkt + 1];
    for (int i = threadIdx.x; i < BNODES; i += 256) cnt[i] = 0;
    __syncthreads();
    for (int e = ebeg + threadIdx.x; e < eend; e += 256)
        atomicAdd(&cnt[tmp[e].x - n0], 1);
    __syncthreads();
    // block exclusive scan over cnt[0..512): thread owns 2 consecutive entries
    int t = threadIdx.x;
    int c0 = cnt[2 * t], c1 = cnt[2 * t + 1];
    int s = c0 + c1;
    int lane = t & 63, wid = t >> 6;
    int x = s;
#pragma unroll
    for (int o = 1; o < 64; o <<= 1) {
        int y = __shfl_up(x, o);
        if (lane >= o) x += y;
    }
    if (lane == 63) wtot[wid] = x;
    __syncthreads();
    if (t == 0) { int a = 0; for (int k = 0; k < 4; ++k) { woff[k] = a; a += wtot[k]; } }
    __syncthreads();
    int eb = woff[wid] + x - s;
    off[2 * t] = eb;
    off[2 * t + 1] = eb + c0;
    __syncthreads();
    for (int i = threadIdx.x; i < nloc; i += 256) {
        rp[n0 + i] = ebeg + off[i];
        int c = cnt[i];
        float fc = (float)c;
        dinv[n0 + i]  = (c > 0) ? rsqrtf(fc) : 0.0f;
        dinv2[n0 + i] = (c > 0) ? 1.0f / fc : 0.0f;
        rinv[n0 + i]  = (c > 0) ? sqrtf(fc) : 0.0f;
    }
    __syncthreads();
    for (int i = threadIdx.x; i < BNODES; i += 256) cnt[i] = 0;  // reuse as fill
    __syncthreads();
    for (int e = ebeg + threadIdx.x; e < eend; e += 256) {
        int2 ed = tmp[e];
        int sl = ed.x - n0;
        int r = atomicAdd(&cnt[sl], 1);
        col[ebeg + off[sl] + r] = ed.y;
    }
}

// ---------------- propagation ----------------
// y_k := dinv .* x_k.  y_{k+1}[s] = dinv2[s] * sum_{d in N(s)} y_k[d]
// MODE 0: layer 1 — gather x0h with per-edge weight dinv[d]; write y1 = dinv2[s]*acc
// MODE 1: mid layer — gather y (no weight); write y_{k+1} = dinv2[s]*acc
// MODE 2: final — gather y2; out = 0.25*(x0 + (y1+y2+y3)*rinv[s]), fp32 write
template <int MODE>
__global__ __launch_bounds__(256)
void k_spmm(const float4* __restrict__ xin, float4* __restrict__ xout,
            const int* __restrict__ rp, const int* __restrict__ col,
            const float* __restrict__ dinv, const float* __restrict__ dinv2,
            const float* __restrict__ rinv,
            const float4* __restrict__ x0h, const float4* __restrict__ y1h,
            float4* __restrict__ outp, int nn) {
    int wave = (blockIdx.x * blockDim.x + threadIdx.x) >> 6;
    int lane = threadIdx.x & 63;
    int g = lane >> 4, l16 = lane & 15;
    int node = wave * 4 + g;
    int beg = 0, end = 0;
    if (node < nn) { beg = rp[node]; end = rp[node + 1]; }
    float acc[8];
#pragma unroll
    for (int k = 0; k < 8; ++k) acc[k] = 0.f;

    int srcl = g << 4;
    for (int base = beg; base < end; base += 16) {
        int p = base + l16;
        int d = 0;
        float wt = 0.f;
        if (p < end) {
            d = col[p];
            if (MODE == 0) wt = dinv[d];
        }
        int m = min(16, end - base);
#pragma unroll 8
        for (int t = 0; t < m; ++t) {
            int dd = __shfl(d, srcl + t);
            float4 rv = xin[(size_t)dd * 16 + l16];
            const __half2* hp = reinterpret_cast<const __half2*>(&rv);
            if (MODE == 0) {
                float wv = __shfl(wt, srcl + t);
#pragma unroll
                for (int k = 0; k < 4; ++k) {
                    float2 f = __half22float2(hp[k]);
                    acc[2 * k]     = fmaf(wv, f.x, acc[2 * k]);
                    acc[2 * k + 1] = fmaf(wv, f.y, acc[2 * k + 1]);
                }
            } else {
#pragma unroll
                for (int k = 0; k < 4; ++k) {
                    float2 f = __half22float2(hp[k]);
                    acc[2 * k]     += f.x;
                    acc[2 * k + 1] += f.y;
                }
            }
        }
    }
    if (node >= nn) return;
    float s2 = dinv2[node];
    if (MODE != 2) {
        __half2 h[4];
#pragma unroll
        for (int k = 0; k < 4; ++k)
            h[k] = __floats2half2_rn(s2 * acc[2 * k], s2 * acc[2 * k + 1]);
        xout[(size_t)node * 16 + l16] = *reinterpret_cast<const float4*>(h);
    } else {
        size_t r16 = (size_t)node * 16 + l16;
        float4 ev = x0h[r16];   // x0 row chunk (fp16)
        float4 av = y1h[r16];   // y1 row chunk (fp16)
        float4 bv = xin[r16];   // y2 row chunk (fp16)
        const __half2* ep = reinterpret_cast<const __half2*>(&ev);
        const __half2* ap = reinterpret_cast<const __half2*>(&av);
        const __half2* bp = reinterpret_cast<const __half2*>(&bv);
        float rv = rinv[node];
        float o[8];
#pragma unroll
        for (int k = 0; k < 4; ++k) {
            float2 fe = __half22float2(ep[k]);
            float2 fa = __half22float2(ap[k]);
            float2 fb = __half22float2(bp[k]);
            // y3 = s2*acc; x-sum = (y1+y2+y3)*rinv
            o[2 * k]     = 0.25f * (fe.x + (fa.x + fb.x + s2 * acc[2 * k]) * rv);
            o[2 * k + 1] = 0.25f * (fe.y + (fa.y + fb.y + s2 * acc[2 * k + 1]) * rv);
        }
        float4 w0 = make_float4(o[0], o[1], o[2], o[3]);
        float4 w1 = make_float4(o[4], o[5], o[6], o[7]);
        size_t r32 = (size_t)node * 32 + 2 * l16;
        outp[r32] = w0;
        outp[r32 + 1] = w1;
    }
}

// ---------------- launch ----------------

extern "C" void kernel_launch(void* const* d_in, const int* in_sizes, int n_in,
                              void* d_out, int out_size, void* d_ws, size_t ws_size,
                              hipStream_t stream) {
    const float* uw = (const float*)d_in[0];
    const float* iw = (const float*)d_in[1];
    const int* ei = (const int*)d_in[2];

    const int NU = in_sizes[0] / D;       // 100000
    const int NI = in_sizes[1] / D;       // 50000
    const int NN = NU + NI;               // 150000
    const int NE2 = in_sizes[2] / 2;      // 2,000,000 directed edges
    const int* src = ei;
    const int* dst = ei + NE2;
    const int NB = (NN + BNODES - 1) >> BSH;   // 293

    char* p = (char*)d_ws;
    auto alloc = [&](size_t bytes) -> void* {
        void* r = (void*)p;
        p += (bytes + 255) & ~(size_t)255;
        return r;
    };
    int* bhist  = (int*)alloc(NBMAX * 4);
    int* bbase  = (int*)alloc((NBMAX + 1) * 4);
    int* bfill  = (int*)alloc(NBMAX * 4);
    int* rp     = (int*)alloc((size_t)(NN + 1) * 4);
    float* dinv = (float*)alloc((size_t)NN * 4);
    float* dinv2= (float*)alloc((size_t)NN * 4);
    float* rinv = (float*)alloc((size_t)NN * 4);
    int2* tmp   = (int2*)alloc((size_t)NE2 * 8);
    int* col    = (int*)alloc((size_t)NE2 * 4);
    __half2* xa = (__half2*)alloc((size_t)NN * D * 2);  // x0h
    __half2* xb = (__half2*)alloc((size_t)NN * D * 2);  // y1
    __half2* xc = (__half2*)alloc((size_t)NN * D * 2);  // y2
    float* outp = (float*)d_out;

    hipMemsetAsync(bhist, 0, NBMAX * 4, stream);

    int ntot2 = NN * (D / 2);
    int nu2 = NU * (D / 2);
    int bce = (NE2 + CCHUNK - 1) / CCHUNK;       // hist blocks
    int bi = (ntot2 + 255) / 256;                // tohalf blocks

    k_hist_tohalf<<<bce + bi, 256, 0, stream>>>(src, bhist, NE2, NB, bce,
                                                (const float2*)uw, (const float2*)iw,
                                                xa, nu2, ntot2);
    k_bscan<<<1, NBMAX, 0, stream>>>(bhist, bbase, bfill, rp, NB, NN, NE2);
    k_scatter<<<bce, 256, 0, stream>>>(src, dst, bfill, tmp, NE2, NB);
    k_build<<<NB, 256, 0, stream>>>(tmp, bbase, col, rp, dinv, dinv2, rinv, NN);

    int bs = (NN + 15) / 16;  // 4 waves/block, 4 nodes per wave
    k_spmm<0><<<bs, 256, 0, stream>>>((const float4*)xa, (float4*)xb, rp, col,
                                      dinv, dinv2, rinv, nullptr, nullptr, nullptr, NN);
    k_spmm<1><<<bs, 256, 0, stream>>>((const float4*)xb, (float4*)xc, rp, col,
                                      dinv, dinv2, rinv, nullptr, nullptr, nullptr, NN);
    k_spmm<2><<<bs, 256, 0, stream>>>((const float4*)xc, nullptr, rp, col,
                                      dinv, dinv2, rinv,
                                      (const float4*)xa, (const float4*)xb,
                                      (float4*)outp, NN);
}

// Round 8
// 391.858 us; speedup vs baseline: 2.2596x; 1.1293x over previous
//
#include <hip/hip_runtime.h>
#include <hip/hip_fp16.h>
#include <cstdint>
#include <cstddef>

#define D 128
#define BSH 9              // 512 nodes per bucket
#define BNODES 512
#define NBMAX 512          // max buckets (supports NN up to 262144)
#define CCHUNK 8192        // edges per block in hist/scatter
#define FP8_SCALE 2048.0f
#define FP8_INV_SCALE (1.0f / 2048.0f)

typedef float v2f __attribute__((ext_vector_type(2)));

static __device__ inline unsigned pack_fp8x4(float a, float b, float c, float d) {
    a = fminf(fmaxf(a, -440.f), 440.f);
    b = fminf(fmaxf(b, -440.f), 440.f);
    c = fminf(fmaxf(c, -440.f), 440.f);
    d = fminf(fmaxf(d, -440.f), 440.f);
    int r = 0;
    r = __builtin_amdgcn_cvt_pk_fp8_f32(a, b, r, false);
    r = __builtin_amdgcn_cvt_pk_fp8_f32(c, d, r, true);
    return (unsigned)r;
}

// ---------------- bucketed CSR build ----------------

// A: per-bucket histogram (blocks [0, nbh)) + emb->fp16 (blocks [nbh, ...))
__global__ __launch_bounds__(256)
void k_hist_tohalf(const int* __restrict__ src, int* __restrict__ bhist,
                   int ne2, int nb, int nbh,
                   const float2* __restrict__ uw, const float2* __restrict__ iw,
                   __half2* __restrict__ x0, int nu2, int ntot2) {
    if ((int)blockIdx.x < nbh) {
        __shared__ int lc[NBMAX];
        for (int i = threadIdx.x; i < nb; i += 256) lc[i] = 0;
        __syncthreads();
        int base = blockIdx.x * CCHUNK;
        int lim = min(base + CCHUNK, ne2);
        for (int e = base + threadIdx.x; e < lim; e += 256)
            atomicAdd(&lc[src[e] >> BSH], 1);
        __syncthreads();
        for (int i = threadIdx.x; i < nb; i += 256)
            if (lc[i]) atomicAdd(&bhist[i], lc[i]);
    } else {
        int g = (blockIdx.x - nbh) * 256 + threadIdx.x;
        if (g < ntot2) {
            float2 v = (g < nu2) ? uw[g] : iw[g - nu2];
            x0[g] = __floats2half2_rn(v.x, v.y);
        }
    }
}

// B: scan bucket counts -> bbase (exclusive), init bfill, write totals
__global__ void k_bscan(const int* __restrict__ bhist, int* __restrict__ bbase,
                        int* __restrict__ bfill, int* __restrict__ rp,
                        int nb, int nn, int ne2) {
    __shared__ int a[NBMAX], b2[NBMAX];
    int t = threadIdx.x;  // NBMAX threads
    int v = (t < nb) ? bhist[t] : 0;
    a[t] = v;
    __syncthreads();
    int* cur = a; int* nxt = b2;
    for (int o = 1; o < NBMAX; o <<= 1) {
        int x = cur[t];
        if (t >= o) x += cur[t - o];
        nxt[t] = x;
        __syncthreads();
        int* tm = cur; cur = nxt; nxt = tm;
    }
    int excl = cur[t] - v;
    if (t < nb) { bbase[t] = excl; bfill[t] = excl; }
    if (t == 0) { bbase[nb] = ne2; rp[nn] = ne2; }
}

// C: scatter edges (packed src_local<<18 | dst) into bucket regions;
// LDS counting-sort per block -> one contiguous run per bucket.
__global__ __launch_bounds__(256)
void k_scatter(const int* __restrict__ src, const int* __restrict__ dst,
               int* __restrict__ bfill, int* __restrict__ tmp, int ne2, int nb) {
    __shared__ int lc[NBMAX], lb[NBMAX];
    for (int i = threadIdx.x; i < nb; i += 256) lc[i] = 0;
    __syncthreads();
    int base = blockIdx.x * CCHUNK;
    int rec[CCHUNK / 256];
#pragma unroll
    for (int i = 0; i < CCHUNK / 256; ++i) {
        int e = base + i * 256 + threadIdx.x;
        rec[i] = -1;
        if (e < ne2) {
            int b = src[e] >> BSH;
            int r = atomicAdd(&lc[b], 1);
            rec[i] = (r << BSH) | b;   // r < 8192 (13b) | b < 512 (9b)
        }
    }
    __syncthreads();
    for (int i = threadIdx.x; i < nb; i += 256)
        if (lc[i]) lb[i] = atomicAdd(&bfill[i], lc[i]);
    __syncthreads();
#pragma unroll
    for (int i = 0; i < CCHUNK / 256; ++i) {
        if (rec[i] >= 0) {
            int e = base + i * 256 + threadIdx.x;
            int b = rec[i] & (BNODES - 1);
            int r = rec[i] >> BSH;
            tmp[lb[b] + r] = ((src[e] & (BNODES - 1)) << 18) | dst[e];
        }
    }
}

// D: one block per bucket: LDS per-node count -> LDS scan -> rp/dinv2/rinv,
// convert the bucket's x0h rows to y0p = fp8(S * dinv * x0),
// then place col into the bucket's L2-resident window.
__global__ __launch_bounds__(256)
void k_build(const int* __restrict__ tmp, const int* __restrict__ bbase,
             int* __restrict__ col, int* __restrict__ rp,
             float* __restrict__ dinv2, float* __restrict__ rinv,
             const float4* __restrict__ x0h, uint2* __restrict__ y0p, int nn) {
    __shared__ int cnt[BNODES];
    __shared__ int off[BNODES];
    __shared__ int wtot[4], woff[4];
    int bkt = blockIdx.x;
    int n0 = bkt << BSH;
    int nloc = min(BNODES, nn - n0);
    int ebeg = bbase[bkt], eend = bbase[bkt + 1];
    for (int i = threadIdx.x; i < BNODES; i += 256) cnt[i] = 0;
    __syncthreads();
    for (int e = ebeg + threadIdx.x; e < eend; e += 256)
        atomicAdd(&cnt[tmp[e] >> 18], 1);
    __syncthreads();
    // block exclusive scan over cnt[0..512): thread owns 2 consecutive entries
    int t = threadIdx.x;
    int c0 = cnt[2 * t], c1 = cnt[2 * t + 1];
    int s = c0 + c1;
    int lane = t & 63, wid = t >> 6;
    int x = s;
#pragma unroll
    for (int o = 1; o < 64; o <<= 1) {
        int y = __shfl_up(x, o);
        if (lane >= o) x += y;
    }
    if (lane == 63) wtot[wid] = x;
    __syncthreads();
    if (t == 0) { int a = 0; for (int k = 0; k < 4; ++k) { woff[k] = a; a += wtot[k]; } }
    __syncthreads();
    int eb = woff[wid] + x - s;
    off[2 * t] = eb;
    off[2 * t + 1] = eb + c0;
    __syncthreads();
    for (int i = threadIdx.x; i < nloc; i += 256) {
        rp[n0 + i] = ebeg + off[i];
        int c = cnt[i];
        float fc = (float)c;
        dinv2[n0 + i] = (c > 0) ? 1.0f / fc : 0.0f;
        rinv[n0 + i]  = (c > 0) ? sqrtf(fc) : 0.0f;
    }
    // y0p = fp8(S * dinv * x0) for this bucket (cnt[] still live)
    {
        int r = threadIdx.x >> 4;
        int l = threadIdx.x & 15;
        for (; r < nloc; r += 16) {
            int c = cnt[r];
            float sc = (c > 0) ? FP8_SCALE * rsqrtf((float)c) : 0.0f;
            float4 v = x0h[(size_t)(n0 + r) * 16 + l];
            const __half2* hp = reinterpret_cast<const __half2*>(&v);
            float2 f0 = __half22float2(hp[0]), f1 = __half22float2(hp[1]);
            float2 f2 = __half22float2(hp[2]), f3 = __half22float2(hp[3]);
            uint2 o;
            o.x = pack_fp8x4(sc * f0.x, sc * f0.y, sc * f1.x, sc * f1.y);
            o.y = pack_fp8x4(sc * f2.x, sc * f2.y, sc * f3.x, sc * f3.y);
            y0p[(size_t)(n0 + r) * 16 + l] = o;
        }
    }
    __syncthreads();
    for (int i = threadIdx.x; i < BNODES; i += 256) cnt[i] = 0;  // reuse as fill
    __syncthreads();
    for (int e = ebeg + threadIdx.x; e < eend; e += 256) {
        int v = tmp[e];
        int sl = v >> 18;
        int r = atomicAdd(&cnt[sl], 1);
        col[ebeg + off[sl] + r] = v & 0x3FFFF;
    }
}

// ---------------- propagation ----------------
// Panels stored S-scaled: ypk = fp8(S*y_k) for gathers; fp16 copies for epilogue.
// y_{k+1}[s] = dinv2[s] * sum_{d in N(s)} y_k[d]   (weight-free in y-space)
// MODE 0: gather y0p -> write y1p (fp8) + y1h (fp16)
// MODE 1: gather y1p -> y2; read own y1h row; write y2p (fp8) + zh = fp16(y1+y2)
// MODE 2: gather y2p -> y3; out = 0.25*(x0 + (zh + y3)*rinv/S), fp32
template <int MODE>
__global__ __launch_bounds__(256)
void k_spmm(const uint2* __restrict__ yin, uint2* __restrict__ y8out,
            float4* __restrict__ h16out, const float4* __restrict__ aux1,
            const float4* __restrict__ aux2,
            const int* __restrict__ rp, const int* __restrict__ col,
            const float* __restrict__ dinv2, const float* __restrict__ rinv,
            float4* __restrict__ outp, int nn) {
    int wave = (blockIdx.x * blockDim.x + threadIdx.x) >> 6;
    int lane = threadIdx.x & 63;
    int g = lane >> 4, l16 = lane & 15;
    int node = wave * 4 + g;
    int beg = 0, end = 0;
    if (node < nn) { beg = rp[node]; end = rp[node + 1]; }
    v2f acc[4];
#pragma unroll
    for (int k = 0; k < 4; ++k) acc[k] = (v2f)(0.f);

    int srcl = g << 4;
    for (int base = beg; base < end; base += 16) {
        int p = base + l16;
        int d = (p < end) ? col[p] : 0;
        int m = min(16, end - base);
#pragma unroll 8
        for (int t = 0; t < m; ++t) {
            int dd = __shfl(d, srcl + t);
            uint2 u = yin[(size_t)dd * 16 + l16];
            acc[0] += __builtin_amdgcn_cvt_pk_f32_fp8((int)u.x, false);
            acc[1] += __builtin_amdgcn_cvt_pk_f32_fp8((int)u.x, true);
            acc[2] += __builtin_amdgcn_cvt_pk_f32_fp8((int)u.y, false);
            acc[3] += __builtin_amdgcn_cvt_pk_f32_fp8((int)u.y, true);
        }
    }
    if (node >= nn) return;
    float s2 = dinv2[node];
    size_t r16 = (size_t)node * 16 + l16;
    if (MODE != 2) {
        float yv[8];
#pragma unroll
        for (int k = 0; k < 4; ++k) {
            yv[2 * k]     = s2 * acc[k].x;
            yv[2 * k + 1] = s2 * acc[k].y;
        }
        uint2 o8;
        o8.x = pack_fp8x4(yv[0], yv[1], yv[2], yv[3]);
        o8.y = pack_fp8x4(yv[4], yv[5], yv[6], yv[7]);
        y8out[r16] = o8;
        if (MODE == 1) {  // zh = fp16(y1 + y2), y1 from own fp16 row
            float4 av = aux1[r16];
            const __half2* ap = reinterpret_cast<const __half2*>(&av);
#pragma unroll
            for (int k = 0; k < 4; ++k) {
                float2 fa = __half22float2(ap[k]);
                yv[2 * k]     += fa.x;
                yv[2 * k + 1] += fa.y;
            }
        }
        __half2 h[4];
#pragma unroll
        for (int k = 0; k < 4; ++k)
            h[k] = __floats2half2_rn(yv[2 * k], yv[2 * k + 1]);
        h16out[r16] = *reinterpret_cast<const float4*>(h);
    } else {
        float4 ev = aux1[r16];   // x0h row chunk
        float4 zv = aux2[r16];   // zh row chunk (S-scaled y1+y2)
        const __half2* ep = reinterpret_cast<const __half2*>(&ev);
        const __half2* zp = reinterpret_cast<const __half2*>(&zv);
        float rs = rinv[node] * FP8_INV_SCALE;
        float o[8];
#pragma unroll
        for (int k = 0; k < 4; ++k) {
            float2 fe = __half22float2(ep[k]);
            float2 fz = __half22float2(zp[k]);
            o[2 * k]     = 0.25f * (fe.x + (fz.x + s2 * acc[k].x) * rs);
            o[2 * k + 1] = 0.25f * (fe.y + (fz.y + s2 * acc[k].y) * rs);
        }
        float4 w0 = make_float4(o[0], o[1], o[2], o[3]);
        float4 w1 = make_float4(o[4], o[5], o[6], o[7]);
        size_t r32 = (size_t)node * 32 + 2 * l16;
        outp[r32] = w0;
        outp[r32 + 1] = w1;
    }
}

// ---------------- launch ----------------

extern "C" void kernel_launch(void* const* d_in, const int* in_sizes, int n_in,
                              void* d_out, int out_size, void* d_ws, size_t ws_size,
                              hipStream_t stream) {
    const float* uw = (const float*)d_in[0];
    const float* iw = (const float*)d_in[1];
    const int* ei = (const int*)d_in[2];

    const int NU = in_sizes[0] / D;       // 100000
    const int NI = in_sizes[1] / D;       // 50000
    const int NN = NU + NI;               // 150000
    const int NE2 = in_sizes[2] / 2;      // 2,000,000 directed edges
    const int* src = ei;
    const int* dst = ei + NE2;
    const int NB = (NN + BNODES - 1) >> BSH;   // 293

    char* p = (char*)d_ws;
    auto alloc = [&](size_t bytes) -> void* {
        void* r = (void*)p;
        p += (bytes + 255) & ~(size_t)255;
        return r;
    };
    int* bhist   = (int*)alloc(NBMAX * 4);
    int* bbase   = (int*)alloc((NBMAX + 1) * 4);
    int* bfill   = (int*)alloc(NBMAX * 4);
    int* rp      = (int*)alloc((size_t)(NN + 1) * 4);
    float* dinv2 = (float*)alloc((size_t)NN * 4);
    float* rinv  = (float*)alloc((size_t)NN * 4);
    int* col     = (int*)alloc((size_t)NE2 * 4);
    __half2* zh  = (__half2*)alloc((size_t)NN * D * 2);  // zh; start aliases tmp
    int* tmp     = (int*)zh;                             // tmp dead before zh written
    __half2* xa  = (__half2*)alloc((size_t)NN * D * 2);  // x0h fp16
    uint2* y0p   = (uint2*)alloc((size_t)NN * D);        // y0 fp8; aliased as y2p
    uint2* y1p   = (uint2*)alloc((size_t)NN * D);        // y1 fp8
    __half2* y1h = (__half2*)alloc((size_t)NN * D * 2);  // y1 fp16 (S-scaled)
    uint2* y2p   = y0p;                                  // y0p dead after spmm<0>
    float* outp  = (float*)d_out;

    hipMemsetAsync(bhist, 0, NBMAX * 4, stream);

    int ntot2 = NN * (D / 2);
    int nu2 = NU * (D / 2);
    int bce = (NE2 + CCHUNK - 1) / CCHUNK;       // hist blocks
    int bi = (ntot2 + 255) / 256;                // tohalf blocks

    k_hist_tohalf<<<bce + bi, 256, 0, stream>>>(src, bhist, NE2, NB, bce,
                                                (const float2*)uw, (const float2*)iw,
                                                xa, nu2, ntot2);
    k_bscan<<<1, NBMAX, 0, stream>>>(bhist, bbase, bfill, rp, NB, NN, NE2);
    k_scatter<<<bce, 256, 0, stream>>>(src, dst, bfill, tmp, NE2, NB);
    k_build<<<NB, 256, 0, stream>>>(tmp, bbase, col, rp, dinv2, rinv,
                                    (const float4*)xa, y0p, NN);

    int bs = (NN + 15) / 16;  // 4 waves/block, 4 nodes per wave
    k_spmm<0><<<bs, 256, 0, stream>>>((const uint2*)y0p, y1p, (float4*)y1h,
                                      nullptr, nullptr, rp, col, dinv2, rinv,
                                      nullptr, NN);
    k_spmm<1><<<bs, 256, 0, stream>>>((const uint2*)y1p, y2p, (float4*)zh,
                                      (const float4*)y1h, nullptr, rp, col,
                                      dinv2, rinv, nullptr, NN);
    k_spmm<2><<<bs, 256, 0, stream>>>((const uint2*)y2p, nullptr, nullptr,
                                      (const float4*)xa, (const float4*)zh,
                                      rp, col, dinv2, rinv, (float4*)outp, NN);
}

// Round 10
// 383.574 us; speedup vs baseline: 2.3084x; 1.0216x over previous
//
#include <hip/hip_runtime.h>
#include <hip/hip_fp16.h>
#include <cstdint>
#include <cstddef>

#define D 128
#define BSH 9              // 512 nodes per bucket
#define BNODES 512
#define NBMAX 512          // max buckets (supports NN up to 262144)
#define CCHUNK 8192        // edges per block in scatter (keeps runs ~28 edges)
#define CCHUNK_H 2048      // edges per block in hist (parallelism)
#define FP8_SCALE 2048.0f
#define FP8_INV_SCALE (1.0f / 2048.0f)

typedef float v2f __attribute__((ext_vector_type(2)));

static __device__ inline unsigned pack_fp8x4(float a, float b, float c, float d) {
    a = fminf(fmaxf(a, -440.f), 440.f);
    b = fminf(fmaxf(b, -440.f), 440.f);
    c = fminf(fmaxf(c, -440.f), 440.f);
    d = fminf(fmaxf(d, -440.f), 440.f);
    int r = 0;
    r = __builtin_amdgcn_cvt_pk_fp8_f32(a, b, r, false);
    r = __builtin_amdgcn_cvt_pk_fp8_f32(c, d, r, true);
    return (unsigned)r;
}

// ---------------- bucketed CSR build ----------------

// A: per-bucket histogram (blocks [0, nbh)) + emb->fp16 (blocks [nbh, ...))
__global__ __launch_bounds__(256)
void k_hist_tohalf(const int* __restrict__ src, int* __restrict__ bhist,
                   int ne2, int nb, int nbh,
                   const float2* __restrict__ uw, const float2* __restrict__ iw,
                   __half2* __restrict__ x0, int nu2, int ntot2) {
    if ((int)blockIdx.x < nbh) {
        __shared__ int lc[NBMAX];
        for (int i = threadIdx.x; i < nb; i += 256) lc[i] = 0;
        __syncthreads();
        int base = blockIdx.x * CCHUNK_H;
        int lim = min(base + CCHUNK_H, ne2);
        for (int e = base + threadIdx.x; e < lim; e += 256)
            atomicAdd(&lc[src[e] >> BSH], 1);
        __syncthreads();
        for (int i = threadIdx.x; i < nb; i += 256)
            if (lc[i]) atomicAdd(&bhist[i], lc[i]);
    } else {
        int g = (blockIdx.x - nbh) * 256 + threadIdx.x;
        if (g < ntot2) {
            float2 v = (g < nu2) ? uw[g] : iw[g - nu2];
            x0[g] = __floats2half2_rn(v.x, v.y);
        }
    }
}

// B: scan bucket counts -> bbase (exclusive), init bfill, write totals
__global__ void k_bscan(const int* __restrict__ bhist, int* __restrict__ bbase,
                        int* __restrict__ bfill, int* __restrict__ rp,
                        int nb, int nn, int ne2) {
    __shared__ int a[NBMAX], b2[NBMAX];
    int t = threadIdx.x;  // NBMAX threads
    int v = (t < nb) ? bhist[t] : 0;
    a[t] = v;
    __syncthreads();
    int* cur = a; int* nxt = b2;
    for (int o = 1; o < NBMAX; o <<= 1) {
        int x = cur[t];
        if (t >= o) x += cur[t - o];
        nxt[t] = x;
        __syncthreads();
        int* tm = cur; cur = nxt; nxt = tm;
    }
    int excl = cur[t] - v;
    if (t < nb) { bbase[t] = excl; bfill[t] = excl; }
    if (t == 0) { bbase[nb] = ne2; rp[nn] = ne2; }
}

// C: scatter edges (packed src_local<<18 | dst) into bucket regions;
// LDS counting-sort per block -> one contiguous run per bucket. 512 threads.
__global__ __launch_bounds__(512)
void k_scatter(const int* __restrict__ src, const int* __restrict__ dst,
               int* __restrict__ bfill, int* __restrict__ tmp, int ne2, int nb) {
    __shared__ int lc[NBMAX], lb[NBMAX];
    for (int i = threadIdx.x; i < nb; i += 512) lc[i] = 0;
    __syncthreads();
    int base = blockIdx.x * CCHUNK;
    int rec[CCHUNK / 512];
#pragma unroll
    for (int i = 0; i < CCHUNK / 512; ++i) {
        int e = base + i * 512 + threadIdx.x;
        rec[i] = -1;
        if (e < ne2) {
            int b = src[e] >> BSH;
            int r = atomicAdd(&lc[b], 1);
            rec[i] = (r << BSH) | b;   // r < 8192 (13b) | b < 512 (9b)
        }
    }
    __syncthreads();
    for (int i = threadIdx.x; i < nb; i += 512)
        if (lc[i]) lb[i] = atomicAdd(&bfill[i], lc[i]);
    __syncthreads();
#pragma unroll
    for (int i = 0; i < CCHUNK / 512; ++i) {
        if (rec[i] >= 0) {
            int e = base + i * 512 + threadIdx.x;
            int b = rec[i] & (BNODES - 1);
            int r = rec[i] >> BSH;
            tmp[lb[b] + r] = ((src[e] & (BNODES - 1)) << 18) | dst[e];
        }
    }
}

// D: one block (512 thr) per bucket: LDS per-node count -> scan -> rp/dinv2/rinv,
// convert the bucket's x0h rows to y0p = fp8(S * dinv * x0),
// then place col into the bucket's L2-resident window.
__global__ __launch_bounds__(512)
void k_build(const int* __restrict__ tmp, const int* __restrict__ bbase,
             int* __restrict__ col, int* __restrict__ rp,
             float* __restrict__ dinv2, float* __restrict__ rinv,
             const float4* __restrict__ x0h, uint2* __restrict__ y0p, int nn) {
    __shared__ int cnt[BNODES];
    __shared__ int off[BNODES];
    __shared__ int wtot[8], woff[8];
    int bkt = blockIdx.x;
    int n0 = bkt << BSH;
    int nloc = min(BNODES, nn - n0);
    int ebeg = bbase[bkt], eend = bbase[bkt + 1];
    int t = threadIdx.x;  // 512 threads
    cnt[t] = 0;
    __syncthreads();
    for (int e = ebeg + t; e < eend; e += 512)
        atomicAdd(&cnt[tmp[e] >> 18], 1);
    __syncthreads();
    // block exclusive scan over cnt[0..512): one entry per thread
    int v = cnt[t];
    int lane = t & 63, wid = t >> 6;
    int x = v;
#pragma unroll
    for (int o = 1; o < 64; o <<= 1) {
        int y = __shfl_up(x, o);
        if (lane >= o) x += y;
    }
    if (lane == 63) wtot[wid] = x;
    __syncthreads();
    if (t == 0) { int a = 0; for (int k = 0; k < 8; ++k) { woff[k] = a; a += wtot[k]; } }
    __syncthreads();
    off[t] = woff[wid] + x - v;   // exclusive
    __syncthreads();
    if (t < nloc) {
        rp[n0 + t] = ebeg + off[t];
        int c = cnt[t];
        float fc = (float)c;
        dinv2[n0 + t] = (c > 0) ? 1.0f / fc : 0.0f;
        rinv[n0 + t]  = (c > 0) ? sqrtf(fc) : 0.0f;
    }
    // y0p = fp8(S * dinv * x0) for this bucket (cnt[] still live)
    {
        int r = t >> 4;
        int l = t & 15;
        for (; r < nloc; r += 32) {
            int c = cnt[r];
            float sc = (c > 0) ? FP8_SCALE * rsqrtf((float)c) : 0.0f;
            float4 fv = x0h[(size_t)(n0 + r) * 16 + l];
            const __half2* hp = reinterpret_cast<const __half2*>(&fv);
            float2 f0 = __half22float2(hp[0]), f1 = __half22float2(hp[1]);
            float2 f2 = __half22float2(hp[2]), f3 = __half22float2(hp[3]);
            uint2 o;
            o.x = pack_fp8x4(sc * f0.x, sc * f0.y, sc * f1.x, sc * f1.y);
            o.y = pack_fp8x4(sc * f2.x, sc * f2.y, sc * f3.x, sc * f3.y);
            y0p[(size_t)(n0 + r) * 16 + l] = o;
        }
    }
    __syncthreads();
    cnt[t] = 0;  // reuse as fill
    __syncthreads();
    for (int e = ebeg + t; e < eend; e += 512) {
        int pv = tmp[e];
        int sl = pv >> 18;
        int r = atomicAdd(&cnt[sl], 1);
        col[ebeg + off[sl] + r] = pv & 0x3FFFF;
    }
}

// ---------------- propagation ----------------
// Gathers always read fp8 S-scaled panels ypk = fp8(S*y_k); running partial sum
// w_k = fp16(x0 + (S*y_1+..+S*y_k)*rinv/S) carries the epilogue in fp16.
// PARTIAL: gather yin; y8out = fp8(dinv2*acc); wout = fp16(win + rs*dinv2*acc)
// FINAL:   gather yin; out = 0.25*(win + rs*dinv2*acc), fp32
template <bool FINAL>
__global__ __launch_bounds__(256)
void k_spmm(const uint2* __restrict__ yin, const float4* __restrict__ win,
            uint2* __restrict__ y8out, float4* __restrict__ wout,
            float4* __restrict__ outp,
            const int* __restrict__ rp, const int* __restrict__ col,
            const float* __restrict__ dinv2, const float* __restrict__ rinv, int nn) {
    int wave = (blockIdx.x * blockDim.x + threadIdx.x) >> 6;
    int lane = threadIdx.x & 63;
    int g = lane >> 4, l16 = lane & 15;
    int node = wave * 4 + g;
    int beg = 0, end = 0;
    if (node < nn) { beg = rp[node]; end = rp[node + 1]; }
    v2f acc[4];
#pragma unroll
    for (int k = 0; k < 4; ++k) acc[k] = (v2f)(0.f);

    int srcl = g << 4;
    for (int base = beg; base < end; base += 16) {
        int p = base + l16;
        int d = (p < end) ? col[p] : 0;
        int m = min(16, end - base);
#pragma unroll 8
        for (int t = 0; t < m; ++t) {
            int dd = __shfl(d, srcl + t);
            uint2 u = yin[(size_t)dd * 16 + l16];
            acc[0] += __builtin_amdgcn_cvt_pk_f32_fp8((int)u.x, false);
            acc[1] += __builtin_amdgcn_cvt_pk_f32_fp8((int)u.x, true);
            acc[2] += __builtin_amdgcn_cvt_pk_f32_fp8((int)u.y, false);
            acc[3] += __builtin_amdgcn_cvt_pk_f32_fp8((int)u.y, true);
        }
    }
    if (node >= nn) return;
    float s2 = dinv2[node];
    float rs = rinv[node] * FP8_INV_SCALE;
    size_t r16 = (size_t)node * 16 + l16;
    float4 wv4 = win[r16];
    const __half2* wp = reinterpret_cast<const __half2*>(&wv4);
    float w[8];
#pragma unroll
    for (int k = 0; k < 4; ++k) {
        float2 fw = __half22float2(wp[k]);
        w[2 * k]     = fw.x + rs * (s2 * acc[k].x);
        w[2 * k + 1] = fw.y + rs * (s2 * acc[k].y);
    }
    if (!FINAL) {
        uint2 o8;
        o8.x = pack_fp8x4(s2 * acc[0].x, s2 * acc[0].y, s2 * acc[1].x, s2 * acc[1].y);
        o8.y = pack_fp8x4(s2 * acc[2].x, s2 * acc[2].y, s2 * acc[3].x, s2 * acc[3].y);
        y8out[r16] = o8;
        __half2 h[4];
#pragma unroll
        for (int k = 0; k < 4; ++k)
            h[k] = __floats2half2_rn(w[2 * k], w[2 * k + 1]);
        wout[r16] = *reinterpret_cast<const float4*>(h);
    } else {
        float4 w0 = make_float4(0.25f * w[0], 0.25f * w[1], 0.25f * w[2], 0.25f * w[3]);
        float4 w1 = make_float4(0.25f * w[4], 0.25f * w[5], 0.25f * w[6], 0.25f * w[7]);
        size_t r32 = (size_t)node * 32 + 2 * l16;
        outp[r32] = w0;
        outp[r32 + 1] = w1;
    }
}

// ---------------- launch ----------------

extern "C" void kernel_launch(void* const* d_in, const int* in_sizes, int n_in,
                              void* d_out, int out_size, void* d_ws, size_t ws_size,
                              hipStream_t stream) {
    const float* uw = (const float*)d_in[0];
    const float* iw = (const float*)d_in[1];
    const int* ei = (const int*)d_in[2];

    const int NU = in_sizes[0] / D;       // 100000
    const int NI = in_sizes[1] / D;       // 50000
    const int NN = NU + NI;               // 150000
    const int NE2 = in_sizes[2] / 2;      // 2,000,000 directed edges
    const int* src = ei;
    const int* dst = ei + NE2;
    const int NB = (NN + BNODES - 1) >> BSH;   // 293

    char* p = (char*)d_ws;
    auto alloc = [&](size_t bytes) -> void* {
        void* r = (void*)p;
        p += (bytes + 255) & ~(size_t)255;
        return r;
    };
    int* bhist   = (int*)alloc(NBMAX * 4);
    int* bbase   = (int*)alloc((NBMAX + 1) * 4);
    int* bfill   = (int*)alloc(NBMAX * 4);
    int* rp      = (int*)alloc((size_t)(NN + 1) * 4);
    float* dinv2 = (float*)alloc((size_t)NN * 4);
    float* rinv  = (float*)alloc((size_t)NN * 4);
    int* col     = (int*)alloc((size_t)NE2 * 4);
    __half2* wh0 = (__half2*)alloc((size_t)NN * D * 2);  // wh0; start aliases tmp
    int* tmp     = (int*)wh0;                            // tmp dead before wh0 written
    __half2* xa  = (__half2*)alloc((size_t)NN * D * 2);  // x0h fp16; later wh1
    uint2* y0p   = (uint2*)alloc((size_t)NN * D);        // y0 fp8; later y2p
    uint2* y1p   = (uint2*)alloc((size_t)NN * D);        // y1 fp8
    __half2* wh1 = xa;                                   // xa dead after spmm<0>
    uint2* y2p   = y0p;                                  // y0p dead after spmm<0>
    float* outp  = (float*)d_out;

    hipMemsetAsync(bhist, 0, NBMAX * 4, stream);

    int ntot2 = NN * (D / 2);
    int nu2 = NU * (D / 2);
    int nbh = (NE2 + CCHUNK_H - 1) / CCHUNK_H;   // hist blocks (977)
    int bi = (ntot2 + 255) / 256;                // tohalf blocks
    int bsc = (NE2 + CCHUNK - 1) / CCHUNK;       // scatter blocks (245)

    k_hist_tohalf<<<nbh + bi, 256, 0, stream>>>(src, bhist, NE2, NB, nbh,
                                                (const float2*)uw, (const float2*)iw,
                                                xa, nu2, ntot2);
    k_bscan<<<1, NBMAX, 0, stream>>>(bhist, bbase, bfill, rp, NB, NN, NE2);
    k_scatter<<<bsc, 512, 0, stream>>>(src, dst, bfill, tmp, NE2, NB);
    k_build<<<NB, 512, 0, stream>>>(tmp, bbase, col, rp, dinv2, rinv,
                                    (const float4*)xa, y0p, NN);

    int bs = (NN + 15) / 16;  // 4 waves/block, 4 nodes per wave
    k_spmm<false><<<bs, 256, 0, stream>>>((const uint2*)y0p, (const float4*)xa,
                                          y1p, (float4*)wh0, nullptr,
                                          rp, col, dinv2, rinv, NN);
    k_spmm<false><<<bs, 256, 0, stream>>>((const uint2*)y1p, (const float4*)wh0,
                                          y2p, (float4*)wh1, nullptr,
                                          rp, col, dinv2, rinv, NN);
    k_spmm<true><<<bs, 256, 0, stream>>>((const uint2*)y2p, (const float4*)wh1,
                                         nullptr, nullptr, (float4*)outp,
                                         rp, col, dinv2, rinv, NN);
}

// Round 11
// 380.584 us; speedup vs baseline: 2.3266x; 1.0079x over previous
//
#include <hip/hip_runtime.h>
#include <hip/hip_fp16.h>
#include <cstdint>
#include <cstddef>

#define D 128
#define BSH 9              // 512 nodes per bucket
#define BNODES 512
#define NBMAX 512          // max buckets (supports NN up to 262144)
#define CCHUNK 4096        // edges per block in scatter
#define CCHUNK_H 2048      // edges per block in hist
#define FP8_SCALE 2048.0f
#define FP8_INV_SCALE (1.0f / 2048.0f)

typedef float v2f __attribute__((ext_vector_type(2)));

static __device__ inline unsigned pack_fp8x4(float a, float b, float c, float d) {
    a = fminf(fmaxf(a, -440.f), 440.f);
    b = fminf(fmaxf(b, -440.f), 440.f);
    c = fminf(fmaxf(c, -440.f), 440.f);
    d = fminf(fmaxf(d, -440.f), 440.f);
    int r = 0;
    r = __builtin_amdgcn_cvt_pk_fp8_f32(a, b, r, false);
    r = __builtin_amdgcn_cvt_pk_fp8_f32(c, d, r, true);
    return (unsigned)r;
}

// ---------------- bucketed CSR build ----------------

// A: per-bucket histogram
__global__ __launch_bounds__(256)
void k_hist(const int* __restrict__ src, int* __restrict__ bhist, int ne2, int nb) {
    __shared__ int lc[NBMAX];
    for (int i = threadIdx.x; i < nb; i += 256) lc[i] = 0;
    __syncthreads();
    int base = blockIdx.x * CCHUNK_H;
    int lim = min(base + CCHUNK_H, ne2);
    for (int e = base + threadIdx.x; e < lim; e += 256)
        atomicAdd(&lc[src[e] >> BSH], 1);
    __syncthreads();
    for (int i = threadIdx.x; i < nb; i += 256)
        if (lc[i]) atomicAdd(&bhist[i], lc[i]);
}

// B: scan bucket counts -> bbase (exclusive), init bfill, write totals
__global__ void k_bscan(const int* __restrict__ bhist, int* __restrict__ bbase,
                        int* __restrict__ bfill, int* __restrict__ rp,
                        int nb, int nn, int ne2) {
    __shared__ int a[NBMAX], b2[NBMAX];
    int t = threadIdx.x;  // NBMAX threads
    int v = (t < nb) ? bhist[t] : 0;
    a[t] = v;
    __syncthreads();
    int* cur = a; int* nxt = b2;
    for (int o = 1; o < NBMAX; o <<= 1) {
        int x = cur[t];
        if (t >= o) x += cur[t - o];
        nxt[t] = x;
        __syncthreads();
        int* tm = cur; cur = nxt; nxt = tm;
    }
    int excl = cur[t] - v;
    if (t < nb) { bbase[t] = excl; bfill[t] = excl; }
    if (t == 0) { bbase[nb] = ne2; rp[nn] = ne2; }
}

// C: scatter edges (packed src_local<<18 | dst) into bucket regions;
// LDS counting-sort per block -> one contiguous run per bucket.
__global__ __launch_bounds__(256)
void k_scatter(const int* __restrict__ src, const int* __restrict__ dst,
               int* __restrict__ bfill, int* __restrict__ tmp, int ne2, int nb) {
    __shared__ int lc[NBMAX], lb[NBMAX];
    for (int i = threadIdx.x; i < nb; i += 256) lc[i] = 0;
    __syncthreads();
    int base = blockIdx.x * CCHUNK;
    int rec[CCHUNK / 256];
#pragma unroll
    for (int i = 0; i < CCHUNK / 256; ++i) {
        int e = base + i * 256 + threadIdx.x;
        rec[i] = -1;
        if (e < ne2) {
            int b = src[e] >> BSH;
            int r = atomicAdd(&lc[b], 1);
            rec[i] = (r << BSH) | b;   // r < 4096 (12b) | b < 512 (9b)
        }
    }
    __syncthreads();
    for (int i = threadIdx.x; i < nb; i += 256)
        if (lc[i]) lb[i] = atomicAdd(&bfill[i], lc[i]);
    __syncthreads();
#pragma unroll
    for (int i = 0; i < CCHUNK / 256; ++i) {
        if (rec[i] >= 0) {
            int e = base + i * 256 + threadIdx.x;
            int b = rec[i] & (BNODES - 1);
            int r = rec[i] >> BSH;
            tmp[lb[b] + r] = ((src[e] & (BNODES - 1)) << 18) | dst[e];
        }
    }
}

// D: one block (512 thr) per bucket: LDS per-node count -> scan -> rp/dinv2/rinv,
// convert the bucket's fp32 emb rows to y0p = fp8(S * dinv * x0),
// then place col into the bucket's L2-resident window.
__global__ __launch_bounds__(512)
void k_build(const int* __restrict__ tmp, const int* __restrict__ bbase,
             int* __restrict__ col, int* __restrict__ rp,
             float* __restrict__ dinv2, float* __restrict__ rinv,
             const float4* __restrict__ uw, const float4* __restrict__ iw,
             uint4* __restrict__ y0p, int nu, int nn) {
    __shared__ int cnt[BNODES];
    __shared__ int off[BNODES];
    __shared__ int wtot[8], woff[8];
    int bkt = blockIdx.x;
    int n0 = bkt << BSH;
    int nloc = min(BNODES, nn - n0);
    int ebeg = bbase[bkt], eend = bbase[bkt + 1];
    int t = threadIdx.x;  // 512 threads
    cnt[t] = 0;
    __syncthreads();
    for (int e = ebeg + t; e < eend; e += 512)
        atomicAdd(&cnt[tmp[e] >> 18], 1);
    __syncthreads();
    // block exclusive scan over cnt[0..512): one entry per thread
    int v = cnt[t];
    int lane = t & 63, wid = t >> 6;
    int x = v;
#pragma unroll
    for (int o = 1; o < 64; o <<= 1) {
        int y = __shfl_up(x, o);
        if (lane >= o) x += y;
    }
    if (lane == 63) wtot[wid] = x;
    __syncthreads();
    if (t == 0) { int a = 0; for (int k = 0; k < 8; ++k) { woff[k] = a; a += wtot[k]; } }
    __syncthreads();
    off[t] = woff[wid] + x - v;   // exclusive
    __syncthreads();
    if (t < nloc) {
        rp[n0 + t] = ebeg + off[t];
        int c = cnt[t];
        float fc = (float)c;
        dinv2[n0 + t] = (c > 0) ? 1.0f / fc : 0.0f;
        rinv[n0 + t]  = (c > 0) ? sqrtf(fc) : 0.0f;
    }
    // y0p = fp8(S * dinv * x0) for this bucket, read fp32 emb (cnt[] still live)
    {
        int r = t >> 3;       // 64 rows per pass
        int l = t & 7;        // lane owns dims 16l..16l+15
        for (; r < nloc; r += 64) {
            int gn = n0 + r;
            int c = cnt[r];
            float sc = (c > 0) ? FP8_SCALE * rsqrtf((float)c) : 0.0f;
            const float4* wb = (gn < nu) ? uw + (size_t)gn * 32
                                         : iw + (size_t)(gn - nu) * 32;
            float4 f0 = wb[l * 4 + 0], f1 = wb[l * 4 + 1];
            float4 f2 = wb[l * 4 + 2], f3 = wb[l * 4 + 3];
            uint4 o;
            o.x = pack_fp8x4(sc * f0.x, sc * f0.y, sc * f0.z, sc * f0.w);
            o.y = pack_fp8x4(sc * f1.x, sc * f1.y, sc * f1.z, sc * f1.w);
            o.z = pack_fp8x4(sc * f2.x, sc * f2.y, sc * f2.z, sc * f2.w);
            o.w = pack_fp8x4(sc * f3.x, sc * f3.y, sc * f3.z, sc * f3.w);
            y0p[(size_t)gn * 8 + l] = o;
        }
    }
    __syncthreads();
    cnt[t] = 0;  // reuse as fill
    __syncthreads();
    for (int e = ebeg + t; e < eend; e += 512) {
        int pv = tmp[e];
        int sl = pv >> 18;
        int r = atomicAdd(&cnt[sl], 1);
        col[ebeg + off[sl] + r] = pv & 0x3FFFF;
    }
}

// ---------------- propagation ----------------
// 8-lane groups: 8 nodes/wave, lane owns 16 dims (uint4 = 16 fp8 / gather).
// Panels S-scaled fp8; running partial w_k = x0 + (S*Σy_j)*rinv/S in fp16.
// MODE 0: win = fp32 emb (uw/iw); write y1p (fp8) + wh0 (fp16)
// MODE 1: win = fp16 wh0; write y2p (fp8) + wh1 (fp16)
// MODE 2: win = fp16 wh1; out = 0.25*w, fp32
template <int MODE>
__global__ __launch_bounds__(256)
void k_spmm(const uint4* __restrict__ yin, const float4* __restrict__ uwf,
            const float4* __restrict__ iwf, const float4* __restrict__ winh,
            uint4* __restrict__ y8out, float4* __restrict__ wout,
            float4* __restrict__ outp,
            const int* __restrict__ rp, const int* __restrict__ col,
            const float* __restrict__ dinv2, const float* __restrict__ rinv,
            int nu, int nn) {
    int wave = (blockIdx.x * blockDim.x + threadIdx.x) >> 6;
    int lane = threadIdx.x & 63;
    int g = lane >> 3, l8 = lane & 7;
    int node = wave * 8 + g;
    int beg = 0, end = 0;
    float s2 = 0.f, rv = 0.f;
    if (node < nn) {
        beg = rp[node]; end = rp[node + 1];
        s2 = dinv2[node]; rv = rinv[node];
    }
    v2f acc[8];
#pragma unroll
    for (int k = 0; k < 8; ++k) acc[k] = (v2f)(0.f);

    int srcl = g << 3;
    for (int base = beg; base < end; base += 8) {
        int p = base + l8;
        int d = (p < end) ? col[p] : 0;
        int m = min(8, end - base);
#pragma unroll 8
        for (int t = 0; t < m; ++t) {
            int dd = __shfl(d, srcl + t);
            uint4 u = yin[(size_t)dd * 8 + l8];
            acc[0] += __builtin_amdgcn_cvt_pk_f32_fp8((int)u.x, false);
            acc[1] += __builtin_amdgcn_cvt_pk_f32_fp8((int)u.x, true);
            acc[2] += __builtin_amdgcn_cvt_pk_f32_fp8((int)u.y, false);
            acc[3] += __builtin_amdgcn_cvt_pk_f32_fp8((int)u.y, true);
            acc[4] += __builtin_amdgcn_cvt_pk_f32_fp8((int)u.z, false);
            acc[5] += __builtin_amdgcn_cvt_pk_f32_fp8((int)u.z, true);
            acc[6] += __builtin_amdgcn_cvt_pk_f32_fp8((int)u.w, false);
            acc[7] += __builtin_amdgcn_cvt_pk_f32_fp8((int)u.w, true);
        }
    }
    if (node >= nn) return;
    float rs = rv * FP8_INV_SCALE;
    float w[16];
    if (MODE == 0) {
        const float4* wb = (node < nu) ? uwf + (size_t)node * 32
                                       : iwf + (size_t)(node - nu) * 32;
        float4 f0 = wb[l8 * 4 + 0], f1 = wb[l8 * 4 + 1];
        float4 f2 = wb[l8 * 4 + 2], f3 = wb[l8 * 4 + 3];
        w[0]=f0.x; w[1]=f0.y; w[2]=f0.z; w[3]=f0.w;
        w[4]=f1.x; w[5]=f1.y; w[6]=f1.z; w[7]=f1.w;
        w[8]=f2.x; w[9]=f2.y; w[10]=f2.z; w[11]=f2.w;
        w[12]=f3.x; w[13]=f3.y; w[14]=f3.z; w[15]=f3.w;
    } else {
        float4 a0 = winh[(size_t)node * 16 + l8 * 2];
        float4 a1 = winh[(size_t)node * 16 + l8 * 2 + 1];
        const __half2* p0 = reinterpret_cast<const __half2*>(&a0);
        const __half2* p1 = reinterpret_cast<const __half2*>(&a1);
#pragma unroll
        for (int k = 0; k < 4; ++k) {
            float2 f = __half22float2(p0[k]);
            w[2 * k] = f.x; w[2 * k + 1] = f.y;
        }
#pragma unroll
        for (int k = 0; k < 4; ++k) {
            float2 f = __half22float2(p1[k]);
            w[8 + 2 * k] = f.x; w[8 + 2 * k + 1] = f.y;
        }
    }
#pragma unroll
    for (int k = 0; k < 8; ++k) {
        w[2 * k]     += rs * (s2 * acc[k].x);
        w[2 * k + 1] += rs * (s2 * acc[k].y);
    }
    if (MODE != 2) {
        uint4 o8;
        o8.x = pack_fp8x4(s2 * acc[0].x, s2 * acc[0].y, s2 * acc[1].x, s2 * acc[1].y);
        o8.y = pack_fp8x4(s2 * acc[2].x, s2 * acc[2].y, s2 * acc[3].x, s2 * acc[3].y);
        o8.z = pack_fp8x4(s2 * acc[4].x, s2 * acc[4].y, s2 * acc[5].x, s2 * acc[5].y);
        o8.w = pack_fp8x4(s2 * acc[6].x, s2 * acc[6].y, s2 * acc[7].x, s2 * acc[7].y);
        y8out[(size_t)node * 8 + l8] = o8;
        __half2 h[8];
#pragma unroll
        for (int k = 0; k < 8; ++k)
            h[k] = __floats2half2_rn(w[2 * k], w[2 * k + 1]);
        wout[(size_t)node * 16 + l8 * 2]     = *reinterpret_cast<const float4*>(&h[0]);
        wout[(size_t)node * 16 + l8 * 2 + 1] = *reinterpret_cast<const float4*>(&h[4]);
    } else {
        size_t r32 = (size_t)node * 32 + l8 * 4;
#pragma unroll
        for (int k = 0; k < 4; ++k) {
            float4 o = make_float4(0.25f * w[4 * k], 0.25f * w[4 * k + 1],
                                   0.25f * w[4 * k + 2], 0.25f * w[4 * k + 3]);
            outp[r32 + k] = o;
        }
    }
}

// ---------------- launch ----------------

extern "C" void kernel_launch(void* const* d_in, const int* in_sizes, int n_in,
                              void* d_out, int out_size, void* d_ws, size_t ws_size,
                              hipStream_t stream) {
    const float* uw = (const float*)d_in[0];
    const float* iw = (const float*)d_in[1];
    const int* ei = (const int*)d_in[2];

    const int NU = in_sizes[0] / D;       // 100000
    const int NI = in_sizes[1] / D;       // 50000
    const int NN = NU + NI;               // 150000
    const int NE2 = in_sizes[2] / 2;      // 2,000,000 directed edges
    const int* src = ei;
    const int* dst = ei + NE2;
    const int NB = (NN + BNODES - 1) >> BSH;   // 293

    char* p = (char*)d_ws;
    auto alloc = [&](size_t bytes) -> void* {
        void* r = (void*)p;
        p += (bytes + 255) & ~(size_t)255;
        return r;
    };
    int* bhist   = (int*)alloc(NBMAX * 4);
    int* bbase   = (int*)alloc((NBMAX + 1) * 4);
    int* bfill   = (int*)alloc(NBMAX * 4);
    int* rp      = (int*)alloc((size_t)(NN + 1) * 4);
    float* dinv2 = (float*)alloc((size_t)NN * 4);
    float* rinv  = (float*)alloc((size_t)NN * 4);
    int* col     = (int*)alloc((size_t)NE2 * 4);
    __half2* wh0 = (__half2*)alloc((size_t)NN * D * 2);  // wh0; start aliases tmp
    int* tmp     = (int*)wh0;                            // tmp dead before wh0 written
    __half2* wh1 = (__half2*)alloc((size_t)NN * D * 2);  // wh1
    uint4* y0p   = (uint4*)alloc((size_t)NN * D);        // y0 fp8; later y2p
    uint4* y1p   = (uint4*)alloc((size_t)NN * D);        // y1 fp8
    uint4* y2p   = y0p;                                  // y0p dead after spmm<0>
    float* outp  = (float*)d_out;

    hipMemsetAsync(bhist, 0, NBMAX * 4, stream);

    int nbh = (NE2 + CCHUNK_H - 1) / CCHUNK_H;   // hist blocks (977)
    int bsc = (NE2 + CCHUNK - 1) / CCHUNK;       // scatter blocks (489)

    k_hist<<<nbh, 256, 0, stream>>>(src, bhist, NE2, NB);
    k_bscan<<<1, NBMAX, 0, stream>>>(bhist, bbase, bfill, rp, NB, NN, NE2);
    k_scatter<<<bsc, 256, 0, stream>>>(src, dst, bfill, tmp, NE2, NB);
    k_build<<<NB, 512, 0, stream>>>(tmp, bbase, col, rp, dinv2, rinv,
                                    (const float4*)uw, (const float4*)iw, y0p, NU, NN);

    int bs = (NN + 31) / 32;  // 4 waves/block, 8 nodes per wave
    k_spmm<0><<<bs, 256, 0, stream>>>((const uint4*)y0p, (const float4*)uw,
                                      (const float4*)iw, nullptr,
                                      y1p, (float4*)wh0, nullptr,
                                      rp, col, dinv2, rinv, NU, NN);
    k_spmm<1><<<bs, 256, 0, stream>>>((const uint4*)y1p, nullptr, nullptr,
                                      (const float4*)wh0,
                                      y2p, (float4*)wh1, nullptr,
                                      rp, col, dinv2, rinv, NU, NN);
    k_spmm<2><<<bs, 256, 0, stream>>>((const uint4*)y2p, nullptr, nullptr,
                                      (const float4*)wh1,
                                      nullptr, nullptr, (float4*)outp,
                                      rp, col, dinv2, rinv, NU, NN);
}